// Round 1
// 4829.867 us; speedup vs baseline: 1.1424x; 1.1424x over previous
//
#include <hip/hip_runtime.h>
#include <hip/hip_bf16.h>
#include <math.h>

#define IDIM 128
#define HDIM 512
#define SDIM 64
#define BATCH 128
#define MAXT 259
#define G4 2048
#define KTOT 704    // 128 (x) + 64 (rt) + 512 (h)
#define ROUT 194    // 64 + 128 + 2
#define AFRAG_U 73728   // 8 mt * 18 ks * 64 lanes * 8 e (uints, hi|lo packed) per buffer
#define NBLK 256
#define PJ 224      // padded j-dim of part (112 uint64 slots per (row,ns))

typedef __hip_bfloat16 bf16;
typedef __attribute__((ext_vector_type(8))) short short8;
typedef __attribute__((ext_vector_type(4))) float floatx4;

__device__ __forceinline__ float sigmoidf_(float v) { return 1.f / (1.f + expf(-v)); }
__device__ __forceinline__ float b2f(bf16 v) { return __bfloat162float(v); }
__device__ __forceinline__ float load_in(const void* p, size_t i, int isf32) {
    return isf32 ? ((const float*)p)[i] : b2f(((const bf16*)p)[i]);
}
__device__ __forceinline__ unsigned short f2bfbits(float v) {
    unsigned u = __builtin_bit_cast(unsigned, v);
    unsigned r = (u + 0x7FFFu + ((u >> 16) & 1u)) >> 16;
    return (unsigned short)r;
}
__device__ __forceinline__ float bfbits2f(unsigned short b) {
    return __builtin_bit_cast(float, (unsigned)b << 16);
}
__device__ __forceinline__ unsigned aload(const unsigned* p) {
    return __hip_atomic_load(p, __ATOMIC_RELAXED, __HIP_MEMORY_SCOPE_AGENT);
}
__device__ __forceinline__ unsigned long long aload64(const unsigned long long* p) {
    return __hip_atomic_load(p, __ATOMIC_RELAXED, __HIP_MEMORY_SCOPE_AGENT);
}
__device__ __forceinline__ void astore64(unsigned long long* p, unsigned long long v) {
    __hip_atomic_store(p, v, __ATOMIC_RELAXED, __HIP_MEMORY_SCOPE_AGENT);
}
__device__ __forceinline__ unsigned long long packf2(float a, float b) {
    return (unsigned long long)__builtin_bit_cast(unsigned, a)
         | ((unsigned long long)__builtin_bit_cast(unsigned, b) << 32);
}
__device__ __forceinline__ void unpack_frag(const unsigned long long* ap,
                                            short8& ah, short8& al) {
    #pragma unroll
    for (int j = 0; j < 4; j++) {
        unsigned long long q = aload64(ap + j);
        unsigned u0 = (unsigned)q, u1 = (unsigned)(q >> 32);
        ah[2 * j]     = (short)(u0 & 0xffffu);
        al[2 * j]     = (short)(u0 >> 16);
        ah[2 * j + 1] = (short)(u1 & 0xffffu);
        al[2 * j + 1] = (short)(u1 >> 16);
    }
}

// Fence-free grid barrier (R9-verified): relaxed-atomic flag array, per-wave
// vmcnt drain orders data stores before flag store. 256 blocks co-resident.
__device__ __forceinline__ void flag_barrier(unsigned* flags, unsigned epoch) {
    asm volatile("s_waitcnt vmcnt(0)" ::: "memory");
    __syncthreads();
    if (threadIdx.x == 0)
        __hip_atomic_store(&flags[blockIdx.x * 16], epoch,
                           __ATOMIC_RELAXED, __HIP_MEMORY_SCOPE_AGENT);
    while (aload(&flags[threadIdx.x * 16]) < epoch)
        __builtin_amdgcn_s_sleep(2);
    __atomic_signal_fence(__ATOMIC_SEQ_CST);
    __syncthreads();
}

// Producer-consumer wait on the per-group rt counter (same ordering idiom:
// producers drain vmcnt before the relaxed fetch_add; consumers poll, fence,
// barrier, then issue fresh agent-scope frag loads).
__device__ __forceinline__ void wait_rtc(unsigned* rtc, int g, unsigned tgt) {
    if (threadIdx.x == 0) {
        while (aload(&rtc[g * 16]) < tgt) __builtin_amdgcn_s_sleep(1);
    }
    __atomic_signal_fence(__ATOMIC_SEQ_CST);
    __syncthreads();
}

// dtype detect (defensive): f32 data has random low halves -> bf16-exp >= 0x8F
__global__ void detect_kernel(const unsigned short* __restrict__ w, int* __restrict__ flag) {
    if (threadIdx.x == 0) {
        int isf32 = 0;
        for (int i = 0; i < 256; i++) {
            int e = (w[i] >> 7) & 0xFF;
            if (e >= 0x8F) isf32 = 1;
        }
        *flag = isf32;
    }
}

// Gate-interleaved combined weights in B-fragment layout (hi/lo bf16 split).
__global__ void prep_kernel(const void* __restrict__ Wih, const void* __restrict__ bih,
                            const void* __restrict__ Whh, const void* __restrict__ bhh,
                            unsigned short* __restrict__ WfH, unsigned short* __restrict__ WfL,
                            float* __restrict__ bc, const int* __restrict__ flag) {
    int isf32 = *flag;
    int jp = blockIdx.x;
    int u = jp >> 2, gate = jp & 3;
    int src = gate * HDIM + u;
    int jt = jp >> 4, jn = jp & 15;
    for (int k = threadIdx.x; k < KTOT; k += blockDim.x) {
        float v = (k < 192) ? load_in(Wih, (size_t)src * 192 + k, isf32)
                            : load_in(Whh, (size_t)src * HDIM + (k - 192), isf32);
        unsigned short hi = f2bfbits(v);
        unsigned short lo = f2bfbits(v - bfbits2f(hi));
        int ks = k >> 5, q = (k & 31) >> 3, e = k & 7;
        size_t d = (((size_t)jt * 22 + ks) * 64 + (q * 16 + jn)) * 8 + e;
        WfH[d] = hi;
        WfL[d] = lo;
    }
    if (threadIdx.x == 0)
        bc[jp] = load_in(bih, src, isf32) + load_in(bhh, src, isf32);
}

// Wr -> row-major bf16 hi/lo (208 rows, rows >=194 zero) + brf f32 (padded).
__global__ void wr_prep_kernel(const void* __restrict__ Wr, const void* __restrict__ br,
                               unsigned short* __restrict__ WrBh, unsigned short* __restrict__ WrBl,
                               float* __restrict__ brf, const int* __restrict__ flag) {
    int isf32 = *flag;
    int j = blockIdx.x;
    for (int k = threadIdx.x; k < HDIM; k += blockDim.x) {
        float v = (j < ROUT) ? load_in(Wr, (size_t)j * HDIM + k, isf32) : 0.f;
        unsigned short hi = f2bfbits(v);
        WrBh[(size_t)j * HDIM + k] = hi;
        WrBl[(size_t)j * HDIM + k] = f2bfbits(v - bfbits2f(hi));
    }
    if (threadIdx.x == 0) brf[j] = (j < ROUT) ? load_in(br, j, isf32) : 0.f;
}

// ---------------- persistent kernel (R12: single barrier per step) ----------------
// 256 blocks x 256 threads. blk = ms*32+ns. One full flag_barrier per timestep;
// the rt(t-1) handoff is a per-group producer-consumer counter rtc[ms] (16 row-
// blocks bump it after publishing rt frags). P2 for step t-1 runs at the TOP of
// iteration t in row-blocks, overlapped with the other blocks' h-staging and
// x/h MFMAs. The rtc poll also guards the `part` WAR: rtc[ms]>=16t <=> the 16
// readers of group-ms partials(t-1) are done, so partials(t) may overwrite.
__global__ __launch_bounds__(256) void persist_kernel(
        const void* __restrict__ x,
        const unsigned short* __restrict__ WfH, const unsigned short* __restrict__ WfL,
        const float* __restrict__ bc,
        const unsigned short* __restrict__ WrBh, const unsigned short* __restrict__ WrBl,
        const float* __restrict__ brf,
        unsigned* __restrict__ AfP,          // 2 x AFRAG_U uints (hi | lo<<16)
        float* __restrict__ part,            // [128 rows][32 ns][PJ j] f32
        unsigned short* __restrict__ Vg,     // [128][259][64] bf16, block-private
        void* __restrict__ dout, const int* __restrict__ flag,
        unsigned* __restrict__ flags, unsigned* __restrict__ rtc) {
    __shared__ __align__(16) short Ahs[18 * 64 * 8];          // staged A hi; pt overlay later
    __shared__ __align__(16) short Als[18 * 64 * 8];          // staged A lo
    __shared__ __align__(16) unsigned short wrsl[208 * 16];   // Wr hi slice (16 cols of ns)
    __shared__ __align__(16) unsigned short wrslL[208 * 16];  // Wr lo slice
    __shared__ __align__(16) float scr[4][16][20];
    __shared__ __align__(16) float hl[16][17];
    __shared__ __align__(16) float outs[208];
    __shared__ __align__(16) float sL[324];
    __shared__ __align__(16) float aL[324];
    __shared__ __align__(16) float red[4][64];
    __shared__ __align__(16) float brS[208];
    __shared__ __align__(16) float bcS[64];

    const int tid = threadIdx.x, lane = tid & 63, wv = tid >> 6;
    const int blk = blockIdx.x, ms = blk >> 5, ns = blk & 31;
    const int isf32 = *flag;
    float* const pt = (float*)Ahs;       // 16 x 212 f32 overlay (13.6KB <= 18.4KB)

    for (int i = tid; i < 208 * 16; i += 256) {
        int j = i >> 4, ui = i & 15;
        wrsl[i]  = WrBh[(size_t)j * HDIM + ns * 16 + ui];
        wrslL[i] = WrBl[(size_t)j * HDIM + ns * 16 + ui];
    }
    for (int i = tid; i < 208; i += 256) brS[i] = brf[i];
    if (tid < 64) bcS[tid] = bc[ns * 64 + tid];
    for (int i = tid; i < 324; i += 256) { sL[i] = 0.f; aL[i] = 0.f; }
    float cc = 0.f;
    __syncthreads();

    const short8* WH = (const short8*)WfH;
    const short8* WL = (const short8*)WfL;
    const int nt = ns * 4 + wv;
    unsigned short* Vrow = Vg + (size_t)blk * MAXT * SDIM;    // blocks 0..127 only

    for (int t = 0; t <= MAXT; t++) {
        const int cur = t & 1, nxt = cur ^ 1;
        const unsigned long long* AfPc64 =
            (const unsigned long long*)(AfP + (size_t)cur * AFRAG_U);
        unsigned long long* AfPn64 =
            (unsigned long long*)(AfP + (size_t)nxt * AFRAG_U);
        unsigned long long* AfCur64 =
            (unsigned long long*)(AfP + (size_t)cur * AFRAG_U);

        // ---- P0a: stage h A-frags (ksi 2..17) from buf cur. Issued before P2
        // in row-blocks so the LLC latency hides under the P2 compute. ----
        if (t < MAXT) {
            for (int i = tid; i < 16 * 64; i += 256) {
                int ksi = 2 + (i >> 6), l = i & 63;
                const unsigned long long* ap =
                    AfPc64 + ((size_t)(ms * 18 + ksi) * 64 + l) * 4;
                short8 ah, al8;
                unpack_frag(ap, ah, al8);
                *(short8*)&Ahs[(ksi * 64 + l) * 8] = ah;
                *(short8*)&Als[(ksi * 64 + l) * 8] = al8;
            }
        }

        // ---- P2 for step t-1 (row-blocks): reduce partials, stack update,
        // rt(t-1) -> buf cur, bump rtc[group]. ----
        if (blk < 128 && t > 0) {
            const int tp = t - 1;
            const int brow = blk;
            const int msb = brow >> 4, mloc = brow & 15;
            if (tid < 208) {
                float s4 = brS[tid];
                const unsigned* pb = (const unsigned*)part + ((size_t)brow * 32) * PJ + tid;
                #pragma unroll 8
                for (int nsI = 0; nsI < 32; nsI++)
                    s4 += __builtin_bit_cast(float, aload(pb + (size_t)nsI * PJ));
                outs[tid] = s4;
            }
            __syncthreads();
            if (wv == 0) {
                float uval = sigmoidf_(outs[192]);
                float dval = sigmoidf_(outs[193]);
                Vrow[tp * SDIM + lane] = f2bfbits(outs[lane]);
                int ebase = lane * 5;
                float sv[5], suf[5];
                #pragma unroll
                for (int j = 0; j < 5; j++) {
                    int e = ebase + j;
                    sv[j] = (e < MAXT) ? sL[e] : 0.f;
                }
                suf[4] = sv[4];
                #pragma unroll
                for (int j = 3; j >= 0; j--) suf[j] = sv[j] + suf[j + 1];
                float ltot = suf[0];
                float accs = ltot;
                #pragma unroll
                for (int off = 1; off < 64; off <<= 1) {
                    float y = __shfl_down(accs, off, 64);
                    if (lane + off < 64) accs += y;
                }
                float after_lane = accs - ltot;
                #pragma unroll
                for (int j = 0; j < 5; j++) {
                    int e = ebase + j;
                    if (e < MAXT) {
                        float prod = after_lane + (suf[j] - sv[j]);
                        float sp = (e == tp) ? dval
                                             : fmaxf(0.f, sv[j] - fmaxf(0.f, uval - prod));
                        float inner = fmaxf(0.f, 1.f - prod - sp);
                        sL[e] = sp;
                        aL[e] = fminf(sp, inner);
                    }
                }
            }
            __syncthreads();
            {
                float racc = 0.f;
                #pragma unroll 2
                for (int i2 = wv; i2 <= tp; i2 += 4)
                    racc += aL[i2] * bfbits2f(Vrow[i2 * SDIM + lane]);
                red[wv][lane] = racc;
            }
            __syncthreads();
            if (wv == 0) {
                float rtv = red[0][lane] + red[1][lane] + red[2][lane] + red[3][lane];
                float rtn = __shfl_down(rtv, 1, 64);
                if ((lane & 1) == 0) {
                    unsigned short hb0 = f2bfbits(rtv);
                    unsigned short lb0 = f2bfbits(rtv - bfbits2f(hb0));
                    unsigned short hb1 = f2bfbits(rtn);
                    unsigned short lb1 = f2bfbits(rtn - bfbits2f(hb1));
                    unsigned u0 = (unsigned)hb0 | ((unsigned)lb0 << 16);
                    unsigned u1 = (unsigned)hb1 | ((unsigned)lb1 << 16);
                    int d0 = lane;
                    int ksi = d0 >> 5, q = (d0 & 31) >> 3, e = d0 & 7;
                    size_t fi = (((size_t)msb * 18 + ksi) * 64 + q * 16 + mloc) * 8 + e;
                    astore64(AfCur64 + fi / 2,
                             (unsigned long long)u0 | ((unsigned long long)u1 << 32));
                }
                // release: drain this wave's rt stores, then bump the group counter
                asm volatile("s_waitcnt vmcnt(0)" ::: "memory");
                if (lane == 0)
                    __hip_atomic_fetch_add(&rtc[msb * 16], 1u,
                                           __ATOMIC_RELAXED, __HIP_MEMORY_SCOPE_AGENT);
            } else if (wv == 1 && tp >= 129) {
                float a = outs[64 + lane];
                float bvv = outs[128 + lane];
                float m = fmaxf(a, bvv);
                #pragma unroll
                for (int off = 32; off; off >>= 1) m = fmaxf(m, __shfl_xor(m, off, 64));
                float e = expf(a - m) + expf(bvv - m);
                #pragma unroll
                for (int off = 32; off; off >>= 1) e += __shfl_xor(e, off, 64);
                float ls = logf(e) + m;
                size_t base = ((size_t)(tp - 129) * BATCH + brow) * IDIM;
                if (isf32) {
                    ((float*)dout)[base + lane] = a - ls;
                    ((float*)dout)[base + lane + 64] = bvv - ls;
                } else {
                    ((bf16*)dout)[base + lane] = __float2bfloat16(a - ls);
                    ((bf16*)dout)[base + lane + 64] = __float2bfloat16(bvv - ls);
                }
            }
        }

        if (t == MAXT) break;   // iteration 259 exists only to run P2 for step 258

        const int use_x = (t < 129);
        __syncthreads();        // h A-frags staged (covers P0a; P2 already synced)

        // ---- P1a: gates MFMA, x + h K-slices ----
        floatx4 acc = {0.f, 0.f, 0.f, 0.f};
        const short8* wb  = WH + (size_t)nt * 22 * 64;
        const short8* wbl = WL + (size_t)nt * 22 * 64;
        if (use_x) {
            int m = lane & 15, q = lane >> 4;
            size_t xrow = ((size_t)t * BATCH + ms * 16 + m) * IDIM + q * 8;
            #pragma unroll
            for (int ks = 0; ks < 4; ks++) {
                short8 a;
                if (isf32) {
                    const float* xf = (const float*)x + xrow + ks * 32;
                    #pragma unroll
                    for (int i = 0; i < 8; i++) a[i] = (short)f2bfbits(xf[i]);
                } else {
                    a = *(const short8*)((const unsigned short*)x + xrow + ks * 32);
                }
                acc = __builtin_amdgcn_mfma_f32_16x16x32_bf16(a, wb[ks * 64 + lane], acc, 0, 0, 0);
                if (isf32)
                    acc = __builtin_amdgcn_mfma_f32_16x16x32_bf16(a, wbl[ks * 64 + lane], acc, 0, 0, 0);
            }
        }
        #pragma unroll 4
        for (int ksi = 2; ksi < 18; ksi++) {
            int ks = 4 + ksi;
            short8 ah  = *(const short8*)&Ahs[(ksi * 64 + lane) * 8];
            short8 al8 = *(const short8*)&Als[(ksi * 64 + lane) * 8];
            short8 bh = wb[ks * 64 + lane];
            acc = __builtin_amdgcn_mfma_f32_16x16x32_bf16(ah, bh, acc, 0, 0, 0);
            acc = __builtin_amdgcn_mfma_f32_16x16x32_bf16(al8, bh, acc, 0, 0, 0);
            if (isf32)
                acc = __builtin_amdgcn_mfma_f32_16x16x32_bf16(ah, wbl[ks * 64 + lane], acc, 0, 0, 0);
        }

        // ---- wait for rt(t-1) from the 16 row-blocks of this ms group ----
        wait_rtc(rtc, ms, 16u * (unsigned)t);

        // ---- P0b: stage rt A-frags (ksi 0..1) from buf cur, finish gates ----
        if (tid < 128) {
            int ksi = tid >> 6, l = tid & 63;
            const unsigned long long* ap =
                AfPc64 + ((size_t)(ms * 18 + ksi) * 64 + l) * 4;
            short8 ah, al8;
            unpack_frag(ap, ah, al8);
            *(short8*)&Ahs[(ksi * 64 + l) * 8] = ah;
            *(short8*)&Als[(ksi * 64 + l) * 8] = al8;
        }
        __syncthreads();
        #pragma unroll
        for (int ksi = 0; ksi < 2; ksi++) {
            int ks = 4 + ksi;
            short8 ah  = *(const short8*)&Ahs[(ksi * 64 + lane) * 8];
            short8 al8 = *(const short8*)&Als[(ksi * 64 + lane) * 8];
            short8 bh = wb[ks * 64 + lane];
            acc = __builtin_amdgcn_mfma_f32_16x16x32_bf16(ah, bh, acc, 0, 0, 0);
            acc = __builtin_amdgcn_mfma_f32_16x16x32_bf16(al8, bh, acc, 0, 0, 0);
            if (isf32)
                acc = __builtin_amdgcn_mfma_f32_16x16x32_bf16(ah, wbl[ks * 64 + lane], acc, 0, 0, 0);
        }

        {
            int n = lane & 15, m0 = (lane >> 4) * 4;
            #pragma unroll
            for (int r = 0; r < 4; r++) scr[wv][m0 + r][n] = acc[r];
        }
        __syncthreads();
        // cell epilogue: thread = (row r, local-u ul); c in one VGPR; h -> hl
        {
            int r = tid >> 4, ul = tid & 15;
            float4 g = *(const float4*)&scr[ul >> 2][r][(ul & 3) * 4];
            float4 bb = *(const float4*)&bcS[ul * 4];
            float c2 = sigmoidf_(g.y + bb.y) * cc + sigmoidf_(g.x + bb.x) * tanhf(g.z + bb.z);
            float h2 = sigmoidf_(g.w + bb.w) * tanhf(c2);
            cc = c2;
            hl[r][ul] = h2;
        }
        __syncthreads();   // hl ready; Ahs (MFMA staging) now dead -> pt overlay OK
        // publish h tile as packed uint64 frag stores (128 threads)
        if (tid < 128) {
            int r = tid >> 3, ulp = (tid & 7) * 2;
            float h0 = hl[r][ulp], h1 = hl[r][ulp + 1];
            unsigned short hb0 = f2bfbits(h0);
            unsigned short lb0 = f2bfbits(h0 - bfbits2f(hb0));
            unsigned short hb1 = f2bfbits(h1);
            unsigned short lb1 = f2bfbits(h1 - bfbits2f(hb1));
            unsigned u0 = (unsigned)hb0 | ((unsigned)lb0 << 16);
            unsigned u1 = (unsigned)hb1 | ((unsigned)lb1 << 16);
            int u_g = ns * 16 + ulp;
            int ksi2 = 2 + (u_g >> 5), q = (u_g & 31) >> 3, e = u_g & 7;
            size_t fi = (((size_t)ms * 18 + ksi2) * 64 + q * 16 + r) * 8 + e;
            astore64(AfPn64 + fi / 2, (unsigned long long)u0 | ((unsigned long long)u1 << 32));
        }
        // readout partials -> LDS tile pt[16][212] (full f32)
        {
            int jset = tid >> 4, r2 = tid & 15;
            float* prow = pt + r2 * 212;
            #pragma unroll
            for (int i = 0; i < 13; i++) {
                int j = jset * 13 + i;
                float p = 0.f;
                #pragma unroll
                for (int k = 0; k < 16; k++) p += bfbits2f(wrsl[j * 16 + k]) * hl[r2][k];
                if (isf32) {
                    #pragma unroll
                    for (int k = 0; k < 16; k++) p += bfbits2f(wrslL[j * 16 + k]) * hl[r2][k];
                }
                prow[j] = p;
            }
        }
        __syncthreads();
        // coalesced publish: wave wv owns rows 4wv..4wv+3; per row two wave-wide
        // lane-contiguous uint64 stores (512B + 320B) -> full 64B sectors.
        // Safe WAR: the rtc poll above guaranteed group-ms readers consumed t-1.
        {
            #pragma unroll
            for (int it = 0; it < 4; it++) {
                int rloc = wv * 4 + it;
                int row = ms * 16 + rloc;
                const float* pr = pt + rloc * 212;
                unsigned long long* pb64 =
                    (unsigned long long*)(part + (((size_t)row * 32) + ns) * PJ);
                astore64(pb64 + lane, packf2(pr[2 * lane], pr[2 * lane + 1]));
                if (lane < 40)
                    astore64(pb64 + 64 + lane,
                             packf2(pr[128 + 2 * lane], pr[129 + 2 * lane]));
            }
        }
        flag_barrier(flags, (unsigned)(t + 1));
    }
}

extern "C" void kernel_launch(void* const* d_in, const int* in_sizes, int n_in,
                              void* d_out, int out_size, void* d_ws, size_t ws_size,
                              hipStream_t stream) {
    const void* x   = d_in[0];
    const void* Wih = d_in[1];
    const void* bih = d_in[2];
    const void* Whh = d_in[3];
    const void* bhh = d_in[4];
    const void* Wr  = d_in[5];
    const void* br  = d_in[6];

    char* base = (char*)d_ws;
    size_t off = 0;
    int* flag = (int*)base;                                   off += 64;
    unsigned* flags = (unsigned*)(base + off);                off += 256 * 64 + 64;
    unsigned* rtc = (unsigned*)(base + off);                  off += 1024;
    unsigned short* WfH  = (unsigned short*)(base + off);     off += (size_t)G4 * KTOT * 2;
    unsigned short* WfL  = (unsigned short*)(base + off);     off += (size_t)G4 * KTOT * 2;
    unsigned short* WrBh = (unsigned short*)(base + off);     off += (size_t)208 * HDIM * 2;
    unsigned short* WrBl = (unsigned short*)(base + off);     off += (size_t)208 * HDIM * 2;
    float* bc   = (float*)(base + off);                       off += G4 * 4;
    float* brf  = (float*)(base + off);                       off += 1024;
    unsigned* AfP = (unsigned*)(base + off);                  size_t af_off = off;
                                                              off += (size_t)2 * AFRAG_U * 4;
    float* part = (float*)(base + off);                       off += (size_t)BATCH * 32 * PJ * 4;
    unsigned short* Vg = (unsigned short*)(base + off);       off += (size_t)BATCH * MAXT * SDIM * 2;
    // total ~15 MB

    hipMemsetAsync(base + 64, 0, 256 * 64 + 64 + 1024, stream);        // flags + rtc
    hipMemsetAsync(base + af_off, 0, (size_t)2 * AFRAG_U * 4, stream); // A-frag buffers

    detect_kernel<<<1, 64, 0, stream>>>((const unsigned short*)Wih, flag);
    prep_kernel<<<G4, 256, 0, stream>>>(Wih, bih, Whh, bhh, WfH, WfL, bc, flag);
    wr_prep_kernel<<<208, 256, 0, stream>>>(Wr, br, WrBh, WrBl, brf, flag);

    persist_kernel<<<NBLK, 256, 0, stream>>>(x, WfH, WfL, bc, WrBh, WrBl, brf,
                                             AfP, part, Vg, d_out, flag, flags, rtc);

    (void)in_sizes; (void)n_in; (void)out_size; (void)ws_size;
}

// Round 2
// 4349.405 us; speedup vs baseline: 1.2686x; 1.1105x over previous
//
#include <hip/hip_runtime.h>
#include <hip/hip_bf16.h>
#include <math.h>

#define IDIM 128
#define HDIM 512
#define SDIM 64
#define BATCH 128
#define MAXT 259
#define G4 2048
#define KTOT 704    // 128 (x) + 64 (rt) + 512 (h)
#define ROUT 194    // 64 + 128 + 2
#define AFRAG_U 73728   // 8 mt * 18 ks * 64 lanes * 8 e (uints, hi|lo packed) per buffer
#define NBLK 256
#define PJ 224      // padded j-dim of part (112 uint64 slots per (row,ns))

typedef __hip_bfloat16 bf16;
typedef __attribute__((ext_vector_type(8))) short short8;
typedef __attribute__((ext_vector_type(4))) float floatx4;

__device__ __forceinline__ float sigmoidf_(float v) { return 1.f / (1.f + expf(-v)); }
__device__ __forceinline__ float b2f(bf16 v) { return __bfloat162float(v); }
__device__ __forceinline__ float load_in(const void* p, size_t i, int isf32) {
    return isf32 ? ((const float*)p)[i] : b2f(((const bf16*)p)[i]);
}
__device__ __forceinline__ unsigned short f2bfbits(float v) {
    unsigned u = __builtin_bit_cast(unsigned, v);
    unsigned r = (u + 0x7FFFu + ((u >> 16) & 1u)) >> 16;
    return (unsigned short)r;
}
__device__ __forceinline__ float bfbits2f(unsigned short b) {
    return __builtin_bit_cast(float, (unsigned)b << 16);
}
__device__ __forceinline__ unsigned aload(const unsigned* p) {
    return __hip_atomic_load(p, __ATOMIC_RELAXED, __HIP_MEMORY_SCOPE_AGENT);
}
__device__ __forceinline__ unsigned long long aload64(const unsigned long long* p) {
    return __hip_atomic_load(p, __ATOMIC_RELAXED, __HIP_MEMORY_SCOPE_AGENT);
}
__device__ __forceinline__ void astore64(unsigned long long* p, unsigned long long v) {
    __hip_atomic_store(p, v, __ATOMIC_RELAXED, __HIP_MEMORY_SCOPE_AGENT);
}
__device__ __forceinline__ unsigned long long packf2(float a, float b) {
    return (unsigned long long)__builtin_bit_cast(unsigned, a)
         | ((unsigned long long)__builtin_bit_cast(unsigned, b) << 32);
}
__device__ __forceinline__ void unpack_frag(const unsigned long long* ap,
                                            short8& ah, short8& al) {
    #pragma unroll
    for (int j = 0; j < 4; j++) {
        unsigned long long q = aload64(ap + j);
        unsigned u0 = (unsigned)q, u1 = (unsigned)(q >> 32);
        ah[2 * j]     = (short)(u0 & 0xffffu);
        al[2 * j]     = (short)(u0 >> 16);
        ah[2 * j + 1] = (short)(u1 & 0xffffu);
        al[2 * j + 1] = (short)(u1 >> 16);
    }
}

// Fence-free grid barrier (R9-verified): relaxed-atomic flag array, per-wave
// vmcnt drain orders data stores before flag store. 256 blocks co-resident.
__device__ __forceinline__ void flag_barrier(unsigned* flags, unsigned epoch) {
    asm volatile("s_waitcnt vmcnt(0)" ::: "memory");
    __syncthreads();
    if (threadIdx.x == 0)
        __hip_atomic_store(&flags[blockIdx.x * 16], epoch,
                           __ATOMIC_RELAXED, __HIP_MEMORY_SCOPE_AGENT);
    while (aload(&flags[threadIdx.x * 16]) < epoch)
        __builtin_amdgcn_s_sleep(2);
    __atomic_signal_fence(__ATOMIC_SEQ_CST);
    __syncthreads();
}

// Producer-consumer wait on the per-group rt counter.
__device__ __forceinline__ void wait_rtc(unsigned* rtc, int g, unsigned tgt) {
    if (threadIdx.x == 0) {
        while (aload(&rtc[g * 16]) < tgt) __builtin_amdgcn_s_sleep(1);
    }
    __atomic_signal_fence(__ATOMIC_SEQ_CST);
    __syncthreads();
}

// dtype detect (defensive): f32 data has random low halves -> bf16-exp >= 0x8F
__global__ void detect_kernel(const unsigned short* __restrict__ w, int* __restrict__ flag) {
    if (threadIdx.x == 0) {
        int isf32 = 0;
        for (int i = 0; i < 256; i++) {
            int e = (w[i] >> 7) & 0xFF;
            if (e >= 0x8F) isf32 = 1;
        }
        *flag = isf32;
    }
}

// Gate-interleaved combined weights in B-fragment layout (hi/lo bf16 split).
__global__ void prep_kernel(const void* __restrict__ Wih, const void* __restrict__ bih,
                            const void* __restrict__ Whh, const void* __restrict__ bhh,
                            unsigned short* __restrict__ WfH, unsigned short* __restrict__ WfL,
                            float* __restrict__ bc, const int* __restrict__ flag) {
    int isf32 = *flag;
    int jp = blockIdx.x;
    int u = jp >> 2, gate = jp & 3;
    int src = gate * HDIM + u;
    int jt = jp >> 4, jn = jp & 15;
    for (int k = threadIdx.x; k < KTOT; k += blockDim.x) {
        float v = (k < 192) ? load_in(Wih, (size_t)src * 192 + k, isf32)
                            : load_in(Whh, (size_t)src * HDIM + (k - 192), isf32);
        unsigned short hi = f2bfbits(v);
        unsigned short lo = f2bfbits(v - bfbits2f(hi));
        int ks = k >> 5, q = (k & 31) >> 3, e = k & 7;
        size_t d = (((size_t)jt * 22 + ks) * 64 + (q * 16 + jn)) * 8 + e;
        WfH[d] = hi;
        WfL[d] = lo;
    }
    if (threadIdx.x == 0)
        bc[jp] = load_in(bih, src, isf32) + load_in(bhh, src, isf32);
}

// Wr -> row-major bf16 hi/lo (208 rows, rows >=194 zero) + brf f32 (padded).
__global__ void wr_prep_kernel(const void* __restrict__ Wr, const void* __restrict__ br,
                               unsigned short* __restrict__ WrBh, unsigned short* __restrict__ WrBl,
                               float* __restrict__ brf, const int* __restrict__ flag) {
    int isf32 = *flag;
    int j = blockIdx.x;
    for (int k = threadIdx.x; k < HDIM; k += blockDim.x) {
        float v = (j < ROUT) ? load_in(Wr, (size_t)j * HDIM + k, isf32) : 0.f;
        unsigned short hi = f2bfbits(v);
        WrBh[(size_t)j * HDIM + k] = hi;
        WrBl[(size_t)j * HDIM + k] = f2bfbits(v - bfbits2f(hi));
    }
    if (threadIdx.x == 0) brf[j] = (j < ROUT) ? load_in(br, j, isf32) : 0.f;
}

// ---------------- persistent kernel (R13: latency-flattened P2) ----------------
// 256 blocks x 256 threads. blk = ms*32+ns. One flag_barrier per timestep; rt
// handoff via per-group counter rtc[ms]. R13 changes: (a) partial-reduce loads
// fully unrolled (32 outstanding) and issued BEFORE the frag staging so both
// LLC exposures overlap; (b) stack einsum restricted to the exact nonzero
// suffix [e0..t] (prod monotone => A==0 below e0); (c) readout partials use
// ds_read_b128 on Wr rows + h in registers; (d) for t<129 only j 0..63 and
// 192..211 of the partials are published (ot unused before step 129).
__global__ __launch_bounds__(256) void persist_kernel(
        const void* __restrict__ x,
        const unsigned short* __restrict__ WfH, const unsigned short* __restrict__ WfL,
        const float* __restrict__ bc,
        const unsigned short* __restrict__ WrBh, const unsigned short* __restrict__ WrBl,
        const float* __restrict__ brf,
        unsigned* __restrict__ AfP,          // 2 x AFRAG_U uints (hi | lo<<16)
        float* __restrict__ part,            // [128 rows][32 ns][PJ j] f32
        unsigned short* __restrict__ Vg,     // [128][259][64] bf16, block-private
        void* __restrict__ dout, const int* __restrict__ flag,
        unsigned* __restrict__ flags, unsigned* __restrict__ rtc) {
    __shared__ __align__(16) short Ahs[18 * 64 * 8];          // staged A hi; pt overlay later
    __shared__ __align__(16) short Als[18 * 64 * 8];          // staged A lo
    __shared__ __align__(16) unsigned short wrsl[208 * 16];   // Wr hi slice (16 cols of ns)
    __shared__ __align__(16) unsigned short wrslL[208 * 16];  // Wr lo slice
    __shared__ __align__(16) float scr[4][16][20];
    __shared__ __align__(16) float hl[16][17];
    __shared__ __align__(16) float outs[208];
    __shared__ __align__(16) float sL[324];
    __shared__ __align__(16) float aL[324];
    __shared__ __align__(16) float red[4][64];
    __shared__ __align__(16) float brS[208];
    __shared__ __align__(16) float bcS[64];
    __shared__ int e0S;

    const int tid = threadIdx.x, lane = tid & 63, wv = tid >> 6;
    const int blk = blockIdx.x, ms = blk >> 5, ns = blk & 31;
    const int isf32 = *flag;
    float* const pt = (float*)Ahs;       // 16 x 212 f32 overlay (13.6KB <= 18.4KB)

    for (int i = tid; i < 208 * 16; i += 256) {
        int j = i >> 4, ui = i & 15;
        wrsl[i]  = WrBh[(size_t)j * HDIM + ns * 16 + ui];
        wrslL[i] = WrBl[(size_t)j * HDIM + ns * 16 + ui];
    }
    for (int i = tid; i < 208; i += 256) brS[i] = brf[i];
    if (tid < 64) bcS[tid] = bc[ns * 64 + tid];
    for (int i = tid; i < 324; i += 256) { sL[i] = 0.f; aL[i] = 0.f; }
    float cc = 0.f;
    __syncthreads();

    const short8* WH = (const short8*)WfH;
    const short8* WL = (const short8*)WfL;
    const int nt = ns * 4 + wv;
    unsigned short* Vrow = Vg + (size_t)blk * MAXT * SDIM;    // blocks 0..127 only

    for (int t = 0; t <= MAXT; t++) {
        const int cur = t & 1, nxt = cur ^ 1;
        const unsigned long long* AfPc64 =
            (const unsigned long long*)(AfP + (size_t)cur * AFRAG_U);
        unsigned long long* AfPn64 =
            (unsigned long long*)(AfP + (size_t)nxt * AFRAG_U);
        unsigned long long* AfCur64 =
            (unsigned long long*)(AfP + (size_t)cur * AFRAG_U);

        const bool do_p2 = (blk < 128 && t > 0);

        // ---- issue partial-reduce loads FIRST (32 outstanding, consumed after
        // staging) so their LLC latency overlaps the frag-staging loads ----
        float pv[32];
        if (do_p2 && tid < 208) {
            const unsigned* pb = (const unsigned*)part + ((size_t)blk * 32) * PJ + tid;
            #pragma unroll
            for (int nsI = 0; nsI < 32; nsI++)
                pv[nsI] = __builtin_bit_cast(float, aload(pb + (size_t)nsI * PJ));
        }

        // ---- P0a: stage h A-frags (ksi 2..17) from buf cur ----
        if (t < MAXT) {
            #pragma unroll
            for (int i0 = 0; i0 < 4; i0++) {
                int i = i0 * 256 + tid;
                int ksi = 2 + (i >> 6), l = i & 63;
                const unsigned long long* ap =
                    AfPc64 + ((size_t)(ms * 18 + ksi) * 64 + l) * 4;
                short8 ah, al8;
                unpack_frag(ap, ah, al8);
                *(short8*)&Ahs[(ksi * 64 + l) * 8] = ah;
                *(short8*)&Als[(ksi * 64 + l) * 8] = al8;
            }
        }

        // ---- P2 for step t-1 (row-blocks): reduce partials, stack update,
        // rt(t-1) -> buf cur, bump rtc[group]. ----
        if (do_p2) {
            const int tp = t - 1;
            const int brow = blk;
            const int msb = brow >> 4, mloc = brow & 15;
            if (tid < 208) {
                float s4 = brS[tid];
                #pragma unroll
                for (int nsI = 0; nsI < 32; nsI++) s4 += pv[nsI];
                outs[tid] = s4;
            }
            __syncthreads();
            if (wv == 0) {
                float uval = sigmoidf_(outs[192]);
                float dval = sigmoidf_(outs[193]);
                Vrow[tp * SDIM + lane] = f2bfbits(outs[lane]);
                int ebase = lane * 5;
                float sv[5], suf[5];
                #pragma unroll
                for (int j = 0; j < 5; j++) {
                    int e = ebase + j;
                    sv[j] = (e < MAXT) ? sL[e] : 0.f;
                }
                suf[4] = sv[4];
                #pragma unroll
                for (int j = 3; j >= 0; j--) suf[j] = sv[j] + suf[j + 1];
                float ltot = suf[0];
                float accs = ltot;
                #pragma unroll
                for (int off = 1; off < 64; off <<= 1) {
                    float y = __shfl_down(accs, off, 64);
                    if (lane + off < 64) accs += y;
                }
                float after_lane = accs - ltot;
                int emin = 0x7fffffff;
                #pragma unroll
                for (int j = 0; j < 5; j++) {
                    int e = ebase + j;
                    if (e <= tp) {
                        float prod = after_lane + (suf[j] - sv[j]);
                        float sp = (e == tp) ? dval
                                             : fmaxf(0.f, sv[j] - fmaxf(0.f, uval - prod));
                        float inner = fmaxf(0.f, 1.f - prod - sp);
                        sL[e] = sp;
                        aL[e] = fminf(sp, inner);
                        // A[e] can be nonzero only where prod < 1 (prod is
                        // monotone non-increasing in e => nonzeros form a
                        // suffix [e0..tp]).
                        if (prod < 1.f && e < emin) emin = e;
                    }
                }
                #pragma unroll
                for (int off = 32; off; off >>= 1) {
                    int o = __shfl_xor(emin, off, 64);
                    emin = o < emin ? o : emin;
                }
                if (lane == 0) e0S = emin;
            }
            __syncthreads();
            {
                const int e0 = e0S;
                float racc = 0.f;
                if (e0 <= tp) {
                    int i2s = e0 + ((wv - e0) & 3);
                    for (int i2 = i2s; i2 <= tp; i2 += 4)
                        racc += aL[i2] * bfbits2f(Vrow[i2 * SDIM + lane]);
                }
                red[wv][lane] = racc;
            }
            __syncthreads();
            if (wv == 0) {
                float rtv = red[0][lane] + red[1][lane] + red[2][lane] + red[3][lane];
                float rtn = __shfl_down(rtv, 1, 64);
                if ((lane & 1) == 0) {
                    unsigned short hb0 = f2bfbits(rtv);
                    unsigned short lb0 = f2bfbits(rtv - bfbits2f(hb0));
                    unsigned short hb1 = f2bfbits(rtn);
                    unsigned short lb1 = f2bfbits(rtn - bfbits2f(hb1));
                    unsigned u0 = (unsigned)hb0 | ((unsigned)lb0 << 16);
                    unsigned u1 = (unsigned)hb1 | ((unsigned)lb1 << 16);
                    int d0 = lane;
                    int ksi = d0 >> 5, q = (d0 & 31) >> 3, e = d0 & 7;
                    size_t fi = (((size_t)msb * 18 + ksi) * 64 + q * 16 + mloc) * 8 + e;
                    astore64(AfCur64 + fi / 2,
                             (unsigned long long)u0 | ((unsigned long long)u1 << 32));
                }
                // release: drain this wave's rt stores, then bump the group counter
                asm volatile("s_waitcnt vmcnt(0)" ::: "memory");
                if (lane == 0)
                    __hip_atomic_fetch_add(&rtc[msb * 16], 1u,
                                           __ATOMIC_RELAXED, __HIP_MEMORY_SCOPE_AGENT);
            } else if (wv == 1 && t - 1 >= 129) {
                const int tp = t - 1;
                float a = outs[64 + lane];
                float bvv = outs[128 + lane];
                float m = fmaxf(a, bvv);
                #pragma unroll
                for (int off = 32; off; off >>= 1) m = fmaxf(m, __shfl_xor(m, off, 64));
                float e = expf(a - m) + expf(bvv - m);
                #pragma unroll
                for (int off = 32; off; off >>= 1) e += __shfl_xor(e, off, 64);
                float ls = logf(e) + m;
                size_t base = ((size_t)(tp - 129) * BATCH + blk) * IDIM;
                if (isf32) {
                    ((float*)dout)[base + lane] = a - ls;
                    ((float*)dout)[base + lane + 64] = bvv - ls;
                } else {
                    ((bf16*)dout)[base + lane] = __float2bfloat16(a - ls);
                    ((bf16*)dout)[base + lane + 64] = __float2bfloat16(bvv - ls);
                }
            }
        }

        if (t == MAXT) break;   // iteration 259 exists only to run P2 for step 258

        const int use_x = (t < 129);
        __syncthreads();        // h A-frags staged (covers P0a; P2 already synced)

        // ---- P1a: gates MFMA, x + h K-slices ----
        floatx4 acc = {0.f, 0.f, 0.f, 0.f};
        const short8* wb  = WH + (size_t)nt * 22 * 64;
        const short8* wbl = WL + (size_t)nt * 22 * 64;
        if (use_x) {
            int m = lane & 15, q = lane >> 4;
            size_t xrow = ((size_t)t * BATCH + ms * 16 + m) * IDIM + q * 8;
            #pragma unroll
            for (int ks = 0; ks < 4; ks++) {
                short8 a;
                if (isf32) {
                    const float* xf = (const float*)x + xrow + ks * 32;
                    #pragma unroll
                    for (int i = 0; i < 8; i++) a[i] = (short)f2bfbits(xf[i]);
                } else {
                    a = *(const short8*)((const unsigned short*)x + xrow + ks * 32);
                }
                acc = __builtin_amdgcn_mfma_f32_16x16x32_bf16(a, wb[ks * 64 + lane], acc, 0, 0, 0);
                if (isf32)
                    acc = __builtin_amdgcn_mfma_f32_16x16x32_bf16(a, wbl[ks * 64 + lane], acc, 0, 0, 0);
            }
        }
        #pragma unroll 4
        for (int ksi = 2; ksi < 18; ksi++) {
            int ks = 4 + ksi;
            short8 ah  = *(const short8*)&Ahs[(ksi * 64 + lane) * 8];
            short8 al8 = *(const short8*)&Als[(ksi * 64 + lane) * 8];
            short8 bh = wb[ks * 64 + lane];
            acc = __builtin_amdgcn_mfma_f32_16x16x32_bf16(ah, bh, acc, 0, 0, 0);
            acc = __builtin_amdgcn_mfma_f32_16x16x32_bf16(al8, bh, acc, 0, 0, 0);
            if (isf32)
                acc = __builtin_amdgcn_mfma_f32_16x16x32_bf16(ah, wbl[ks * 64 + lane], acc, 0, 0, 0);
        }

        // ---- wait for rt(t-1) from the 16 row-blocks of this ms group ----
        wait_rtc(rtc, ms, 16u * (unsigned)t);

        // ---- P0b: stage rt A-frags (ksi 0..1) from buf cur, finish gates ----
        if (tid < 128) {
            int ksi = tid >> 6, l = tid & 63;
            const unsigned long long* ap =
                AfPc64 + ((size_t)(ms * 18 + ksi) * 64 + l) * 4;
            short8 ah, al8;
            unpack_frag(ap, ah, al8);
            *(short8*)&Ahs[(ksi * 64 + l) * 8] = ah;
            *(short8*)&Als[(ksi * 64 + l) * 8] = al8;
        }
        __syncthreads();
        #pragma unroll
        for (int ksi = 0; ksi < 2; ksi++) {
            int ks = 4 + ksi;
            short8 ah  = *(const short8*)&Ahs[(ksi * 64 + lane) * 8];
            short8 al8 = *(const short8*)&Als[(ksi * 64 + lane) * 8];
            short8 bh = wb[ks * 64 + lane];
            acc = __builtin_amdgcn_mfma_f32_16x16x32_bf16(ah, bh, acc, 0, 0, 0);
            acc = __builtin_amdgcn_mfma_f32_16x16x32_bf16(al8, bh, acc, 0, 0, 0);
            if (isf32)
                acc = __builtin_amdgcn_mfma_f32_16x16x32_bf16(ah, wbl[ks * 64 + lane], acc, 0, 0, 0);
        }

        {
            int n = lane & 15, m0 = (lane >> 4) * 4;
            #pragma unroll
            for (int r = 0; r < 4; r++) scr[wv][m0 + r][n] = acc[r];
        }
        __syncthreads();
        // cell epilogue: thread = (row r, local-u ul); c in one VGPR; h -> hl
        {
            int r = tid >> 4, ul = tid & 15;
            float4 g = *(const float4*)&scr[ul >> 2][r][(ul & 3) * 4];
            float4 bb = *(const float4*)&bcS[ul * 4];
            float c2 = sigmoidf_(g.y + bb.y) * cc + sigmoidf_(g.x + bb.x) * tanhf(g.z + bb.z);
            float h2 = sigmoidf_(g.w + bb.w) * tanhf(c2);
            cc = c2;
            hl[r][ul] = h2;
        }
        __syncthreads();   // hl ready; Ahs (MFMA staging) now dead -> pt overlay OK
        // publish h tile as packed uint64 frag stores (128 threads)
        if (tid < 128) {
            int r = tid >> 3, ulp = (tid & 7) * 2;
            float h0 = hl[r][ulp], h1 = hl[r][ulp + 1];
            unsigned short hb0 = f2bfbits(h0);
            unsigned short lb0 = f2bfbits(h0 - bfbits2f(hb0));
            unsigned short hb1 = f2bfbits(h1);
            unsigned short lb1 = f2bfbits(h1 - bfbits2f(hb1));
            unsigned u0 = (unsigned)hb0 | ((unsigned)lb0 << 16);
            unsigned u1 = (unsigned)hb1 | ((unsigned)lb1 << 16);
            int u_g = ns * 16 + ulp;
            int ksi2 = 2 + (u_g >> 5), q = (u_g & 31) >> 3, e = u_g & 7;
            size_t fi = (((size_t)ms * 18 + ksi2) * 64 + q * 16 + r) * 8 + e;
            astore64(AfPn64 + fi / 2, (unsigned long long)u0 | ((unsigned long long)u1 << 32));
        }
        // readout partials -> LDS tile pt[16][212]: Wr rows via ds_read_b128,
        // h cached in registers (was ~208 scalar ds_read_u16 per thread).
        {
            int jset = tid >> 4, r2 = tid & 15;
            float hreg[16];
            #pragma unroll
            for (int k = 0; k < 16; k++) hreg[k] = hl[r2][k];
            float* prow = pt + r2 * 212;
            #pragma unroll 4
            for (int i = 0; i < 13; i++) {
                int j = jset * 13 + i;
                short8 w0 = *(const short8*)&wrsl[j * 16];
                short8 w1 = *(const short8*)&wrsl[j * 16 + 8];
                float p = 0.f;
                #pragma unroll
                for (int k = 0; k < 8; k++) p += bfbits2f((unsigned short)w0[k]) * hreg[k];
                #pragma unroll
                for (int k = 0; k < 8; k++) p += bfbits2f((unsigned short)w1[k]) * hreg[8 + k];
                if (isf32) {
                    short8 l0 = *(const short8*)&wrslL[j * 16];
                    short8 l1 = *(const short8*)&wrslL[j * 16 + 8];
                    #pragma unroll
                    for (int k = 0; k < 8; k++) p += bfbits2f((unsigned short)l0[k]) * hreg[k];
                    #pragma unroll
                    for (int k = 0; k < 8; k++) p += bfbits2f((unsigned short)l1[k]) * hreg[8 + k];
                }
                prow[j] = p;
            }
        }
        __syncthreads();
        // coalesced publish: wave wv owns rows 4wv..4wv+3. For t<129 the ot
        // logits (j 64..191) are never consumed -> publish only j 0..63 and
        // 192..211 (readers of the skipped range see stale data summed into
        // outs[64..191], which is unused for tp<129).
        // Safe WAR: the rtc poll above guaranteed group-ms readers consumed t-1.
        {
            #pragma unroll
            for (int it = 0; it < 4; it++) {
                int rloc = wv * 4 + it;
                int row = ms * 16 + rloc;
                const float* pr = pt + rloc * 212;
                unsigned long long* pb64 =
                    (unsigned long long*)(part + (((size_t)row * 32) + ns) * PJ);
                if (use_x) {
                    if (lane < 32)
                        astore64(pb64 + lane, packf2(pr[2 * lane], pr[2 * lane + 1]));
                    else if (lane < 42) {
                        int l2 = lane - 32;   // u64 slots 96..105 = j 192..211
                        astore64(pb64 + 96 + l2,
                                 packf2(pr[192 + 2 * l2], pr[193 + 2 * l2]));
                    }
                } else {
                    astore64(pb64 + lane, packf2(pr[2 * lane], pr[2 * lane + 1]));
                    if (lane < 40)
                        astore64(pb64 + 64 + lane,
                                 packf2(pr[128 + 2 * lane], pr[129 + 2 * lane]));
                }
            }
        }
        flag_barrier(flags, (unsigned)(t + 1));
    }
}

extern "C" void kernel_launch(void* const* d_in, const int* in_sizes, int n_in,
                              void* d_out, int out_size, void* d_ws, size_t ws_size,
                              hipStream_t stream) {
    const void* x   = d_in[0];
    const void* Wih = d_in[1];
    const void* bih = d_in[2];
    const void* Whh = d_in[3];
    const void* bhh = d_in[4];
    const void* Wr  = d_in[5];
    const void* br  = d_in[6];

    char* base = (char*)d_ws;
    size_t off = 0;
    int* flag = (int*)base;                                   off += 64;
    unsigned* flags = (unsigned*)(base + off);                off += 256 * 64 + 64;
    unsigned* rtc = (unsigned*)(base + off);                  off += 1024;
    unsigned short* WfH  = (unsigned short*)(base + off);     off += (size_t)G4 * KTOT * 2;
    unsigned short* WfL  = (unsigned short*)(base + off);     off += (size_t)G4 * KTOT * 2;
    unsigned short* WrBh = (unsigned short*)(base + off);     off += (size_t)208 * HDIM * 2;
    unsigned short* WrBl = (unsigned short*)(base + off);     off += (size_t)208 * HDIM * 2;
    float* bc   = (float*)(base + off);                       off += G4 * 4;
    float* brf  = (float*)(base + off);                       off += 1024;
    unsigned* AfP = (unsigned*)(base + off);                  size_t af_off = off;
                                                              off += (size_t)2 * AFRAG_U * 4;
    float* part = (float*)(base + off);                       off += (size_t)BATCH * 32 * PJ * 4;
    unsigned short* Vg = (unsigned short*)(base + off);       off += (size_t)BATCH * MAXT * SDIM * 2;
    // total ~15 MB

    hipMemsetAsync(base + 64, 0, 256 * 64 + 64 + 1024, stream);        // flags + rtc
    hipMemsetAsync(base + af_off, 0, (size_t)2 * AFRAG_U * 4, stream); // A-frag buffers
    hipMemsetAsync(part, 0, (size_t)BATCH * 32 * PJ * 4, stream);      // stale-read hygiene

    detect_kernel<<<1, 64, 0, stream>>>((const unsigned short*)Wih, flag);
    prep_kernel<<<G4, 256, 0, stream>>>(Wih, bih, Whh, bhh, WfH, WfL, bc, flag);
    wr_prep_kernel<<<208, 256, 0, stream>>>(Wr, br, WrBh, WrBl, brf, flag);

    persist_kernel<<<NBLK, 256, 0, stream>>>(x, WfH, WfL, bc, WrBh, WrBl, brf,
                                             AfP, part, Vg, d_out, flag, flags, rtc);

    (void)in_sizes; (void)n_in; (void)out_size; (void)ws_size;
}

// Round 3
// 4187.198 us; speedup vs baseline: 1.3177x; 1.0387x over previous
//
#include <hip/hip_runtime.h>
#include <hip/hip_bf16.h>
#include <math.h>

#define IDIM 128
#define HDIM 512
#define SDIM 64
#define BATCH 128
#define MAXT 259
#define G4 2048
#define KTOT 704    // 128 (x) + 64 (rt) + 512 (h)
#define ROUT 194    // 64 + 128 + 2
#define AFRAG_U 73728   // 8 mt * 18 ks * 64 lanes * 8 e (uints, hi|lo packed) per buffer
#define NBLK 256
#define PJ 224      // padded j-dim of part (112 uint64 slots per (row,ns))

typedef __hip_bfloat16 bf16;
typedef __attribute__((ext_vector_type(8))) short short8;
typedef __attribute__((ext_vector_type(4))) float floatx4;

__device__ __forceinline__ float sigmoidf_(float v) { return 1.f / (1.f + expf(-v)); }
__device__ __forceinline__ float b2f(bf16 v) { return __bfloat162float(v); }
__device__ __forceinline__ float load_in(const void* p, size_t i, int isf32) {
    return isf32 ? ((const float*)p)[i] : b2f(((const bf16*)p)[i]);
}
__device__ __forceinline__ unsigned short f2bfbits(float v) {
    unsigned u = __builtin_bit_cast(unsigned, v);
    unsigned r = (u + 0x7FFFu + ((u >> 16) & 1u)) >> 16;
    return (unsigned short)r;
}
__device__ __forceinline__ float bfbits2f(unsigned short b) {
    return __builtin_bit_cast(float, (unsigned)b << 16);
}
__device__ __forceinline__ unsigned aload(const unsigned* p) {
    return __hip_atomic_load(p, __ATOMIC_RELAXED, __HIP_MEMORY_SCOPE_AGENT);
}
__device__ __forceinline__ unsigned long long aload64(const unsigned long long* p) {
    return __hip_atomic_load(p, __ATOMIC_RELAXED, __HIP_MEMORY_SCOPE_AGENT);
}
__device__ __forceinline__ void astore64(unsigned long long* p, unsigned long long v) {
    __hip_atomic_store(p, v, __ATOMIC_RELAXED, __HIP_MEMORY_SCOPE_AGENT);
}
__device__ __forceinline__ unsigned long long packf2(float a, float b) {
    return (unsigned long long)__builtin_bit_cast(unsigned, a)
         | ((unsigned long long)__builtin_bit_cast(unsigned, b) << 32);
}
__device__ __forceinline__ void unpack_frag(const unsigned long long* ap,
                                            short8& ah, short8& al) {
    #pragma unroll
    for (int j = 0; j < 4; j++) {
        unsigned long long q = aload64(ap + j);
        unsigned u0 = (unsigned)q, u1 = (unsigned)(q >> 32);
        ah[2 * j]     = (short)(u0 & 0xffffu);
        al[2 * j]     = (short)(u0 >> 16);
        ah[2 * j + 1] = (short)(u1 & 0xffffu);
        al[2 * j + 1] = (short)(u1 >> 16);
    }
}

// Per-GROUP fence-free barrier (32 blocks of one ms group). Per-wave vmcnt
// drain orders data stores before the flag store; only 32 threads poll the
// group's 32 flags (8x less LLC poll traffic than the old grid barrier).
__device__ __forceinline__ void group_barrier(unsigned* flags, int gbase,
                                              unsigned epoch) {
    asm volatile("s_waitcnt vmcnt(0)" ::: "memory");
    __syncthreads();
    if (threadIdx.x == 0)
        __hip_atomic_store(&flags[blockIdx.x * 16], epoch,
                           __ATOMIC_RELAXED, __HIP_MEMORY_SCOPE_AGENT);
    if (threadIdx.x < 32) {
        while (aload(&flags[(gbase + threadIdx.x) * 16]) < epoch)
            __builtin_amdgcn_s_sleep(2);
    }
    __atomic_signal_fence(__ATOMIC_SEQ_CST);
    __syncthreads();
}

// Wait for the 16 per-row rt epoch flags of this group (no RMW serialization:
// each producer stores its own flag; 16 consumer lanes each poll one flag).
__device__ __forceinline__ void wait_rtf(unsigned* rtcf, int ms, unsigned tgt) {
    if (threadIdx.x < 16) {
        while (aload(&rtcf[(ms * 16 + threadIdx.x) * 16]) < tgt)
            __builtin_amdgcn_s_sleep(1);
    }
    __atomic_signal_fence(__ATOMIC_SEQ_CST);
    __syncthreads();
}

// dtype detect (defensive): f32 data has random low halves -> bf16-exp >= 0x8F
__global__ void detect_kernel(const unsigned short* __restrict__ w, int* __restrict__ flag) {
    if (threadIdx.x == 0) {
        int isf32 = 0;
        for (int i = 0; i < 256; i++) {
            int e = (w[i] >> 7) & 0xFF;
            if (e >= 0x8F) isf32 = 1;
        }
        *flag = isf32;
    }
}

// Gate-interleaved combined weights in B-fragment layout (hi/lo bf16 split).
__global__ void prep_kernel(const void* __restrict__ Wih, const void* __restrict__ bih,
                            const void* __restrict__ Whh, const void* __restrict__ bhh,
                            unsigned short* __restrict__ WfH, unsigned short* __restrict__ WfL,
                            float* __restrict__ bc, const int* __restrict__ flag) {
    int isf32 = *flag;
    int jp = blockIdx.x;
    int u = jp >> 2, gate = jp & 3;
    int src = gate * HDIM + u;
    int jt = jp >> 4, jn = jp & 15;
    for (int k = threadIdx.x; k < KTOT; k += blockDim.x) {
        float v = (k < 192) ? load_in(Wih, (size_t)src * 192 + k, isf32)
                            : load_in(Whh, (size_t)src * HDIM + (k - 192), isf32);
        unsigned short hi = f2bfbits(v);
        unsigned short lo = f2bfbits(v - bfbits2f(hi));
        int ks = k >> 5, q = (k & 31) >> 3, e = k & 7;
        size_t d = (((size_t)jt * 22 + ks) * 64 + (q * 16 + jn)) * 8 + e;
        WfH[d] = hi;
        WfL[d] = lo;
    }
    if (threadIdx.x == 0)
        bc[jp] = load_in(bih, src, isf32) + load_in(bhh, src, isf32);
}

// Wr -> row-major bf16 hi/lo (208 rows, rows >=194 zero) + brf f32 (padded).
__global__ void wr_prep_kernel(const void* __restrict__ Wr, const void* __restrict__ br,
                               unsigned short* __restrict__ WrBh, unsigned short* __restrict__ WrBl,
                               float* __restrict__ brf, const int* __restrict__ flag) {
    int isf32 = *flag;
    int j = blockIdx.x;
    for (int k = threadIdx.x; k < HDIM; k += blockDim.x) {
        float v = (j < ROUT) ? load_in(Wr, (size_t)j * HDIM + k, isf32) : 0.f;
        unsigned short hi = f2bfbits(v);
        WrBh[(size_t)j * HDIM + k] = hi;
        WrBl[(size_t)j * HDIM + k] = f2bfbits(v - bfbits2f(hi));
    }
    if (threadIdx.x == 0) brf[j] = (j < ROUT) ? load_in(br, j, isf32) : 0.f;
}

// -------------- persistent kernel (R14: 8 independent groups) --------------
// 256 blocks x 256 threads; group g = ms = blk>>5 owns batch rows 16ms..+15
// and ALL of their dataflow (h-frags, partials, rt, Vg rows, outputs). P2 for
// row ms*16+ns runs on block (ms, ns) for ns<16 -> P2 load spread over all 8
// groups, 16 P2 + 16 light blocks each. Sync: one per-GROUP 32-block barrier
// per timestep + 16 per-row rt epoch flags. Groups are fully decoupled.
__global__ __launch_bounds__(256) void persist_kernel(
        const void* __restrict__ x,
        const unsigned short* __restrict__ WfH, const unsigned short* __restrict__ WfL,
        const float* __restrict__ bc,
        const unsigned short* __restrict__ WrBh, const unsigned short* __restrict__ WrBl,
        const float* __restrict__ brf,
        unsigned* __restrict__ AfP,          // 2 x AFRAG_U uints (hi | lo<<16)
        float* __restrict__ part,            // [128 rows][32 ns][PJ j] f32
        unsigned short* __restrict__ Vg,     // [128][259][64] bf16, row-private
        void* __restrict__ dout, const int* __restrict__ flag,
        unsigned* __restrict__ flags, unsigned* __restrict__ rtcf) {
    __shared__ __align__(16) short Ahs[18 * 64 * 8];          // staged A hi; pt overlay later
    __shared__ __align__(16) short Als[18 * 64 * 8];          // staged A lo
    __shared__ __align__(16) unsigned short wrsl[208 * 16];   // Wr hi slice (16 cols of ns)
    __shared__ __align__(16) unsigned short wrslL[208 * 16];  // Wr lo slice
    __shared__ __align__(16) float scr[4][16][20];
    __shared__ __align__(16) float hl[16][17];
    __shared__ __align__(16) float outs[208];
    __shared__ __align__(16) float sL[324];
    __shared__ __align__(16) float aL[324];
    __shared__ __align__(16) float red[4][64];
    __shared__ __align__(16) float brS[208];
    __shared__ __align__(16) float bcS[64];
    __shared__ int e0S;

    const int tid = threadIdx.x, lane = tid & 63, wv = tid >> 6;
    const int blk = blockIdx.x, ms = blk >> 5, ns = blk & 31;
    const int gbase = ms * 32;               // group's flag base
    const int isf32 = *flag;
    float* const pt = (float*)Ahs;       // 16 x 212 f32 overlay (13.6KB <= 18.4KB)

    const int is_p2 = (ns < 16);
    const int brow = ms * 16 + ns;           // valid when is_p2

    for (int i = tid; i < 208 * 16; i += 256) {
        int j = i >> 4, ui = i & 15;
        wrsl[i]  = WrBh[(size_t)j * HDIM + ns * 16 + ui];
        wrslL[i] = WrBl[(size_t)j * HDIM + ns * 16 + ui];
    }
    for (int i = tid; i < 208; i += 256) brS[i] = brf[i];
    if (tid < 64) bcS[tid] = bc[ns * 64 + tid];
    for (int i = tid; i < 324; i += 256) { sL[i] = 0.f; aL[i] = 0.f; }
    float cc = 0.f;
    __syncthreads();

    const short8* WH = (const short8*)WfH;
    const short8* WL = (const short8*)WfL;
    const int nt = ns * 4 + wv;
    unsigned short* Vrow = Vg + (size_t)(is_p2 ? brow : 0) * MAXT * SDIM;

    for (int t = 0; t <= MAXT; t++) {
        const int cur = t & 1, nxt = cur ^ 1;
        const unsigned long long* AfPc64 =
            (const unsigned long long*)(AfP + (size_t)cur * AFRAG_U);
        unsigned long long* AfPn64 =
            (unsigned long long*)(AfP + (size_t)nxt * AFRAG_U);
        unsigned long long* AfCur64 =
            (unsigned long long*)(AfP + (size_t)cur * AFRAG_U);

        const bool do_p2 = (is_p2 && t > 0);

        // ---- issue partial-reduce loads FIRST (32 outstanding, consumed after
        // staging) so their LLC latency overlaps the frag-staging loads ----
        float pv[32];
        if (do_p2 && tid < 208) {
            const unsigned* pb = (const unsigned*)part + ((size_t)brow * 32) * PJ + tid;
            #pragma unroll
            for (int nsI = 0; nsI < 32; nsI++)
                pv[nsI] = __builtin_bit_cast(float, aload(pb + (size_t)nsI * PJ));
        }

        // ---- P0a: stage h A-frags (ksi 2..17) from buf cur ----
        if (t < MAXT) {
            #pragma unroll
            for (int i0 = 0; i0 < 4; i0++) {
                int i = i0 * 256 + tid;
                int ksi = 2 + (i >> 6), l = i & 63;
                const unsigned long long* ap =
                    AfPc64 + ((size_t)(ms * 18 + ksi) * 64 + l) * 4;
                short8 ah, al8;
                unpack_frag(ap, ah, al8);
                *(short8*)&Ahs[(ksi * 64 + l) * 8] = ah;
                *(short8*)&Als[(ksi * 64 + l) * 8] = al8;
            }
        }

        // ---- P2 for step t-1 (ns<16 blocks): reduce partials, stack update,
        // rt(t-1) -> buf cur, publish per-row epoch flag. ----
        if (do_p2) {
            const int tp = t - 1;
            if (tid < 208) {
                float s4 = brS[tid];
                #pragma unroll
                for (int nsI = 0; nsI < 32; nsI++) s4 += pv[nsI];
                outs[tid] = s4;
            }
            __syncthreads();
            if (wv == 0) {
                float uval = sigmoidf_(outs[192]);
                float dval = sigmoidf_(outs[193]);
                Vrow[tp * SDIM + lane] = f2bfbits(outs[lane]);
                int ebase = lane * 5;
                float sv[5], suf[5];
                #pragma unroll
                for (int j = 0; j < 5; j++) {
                    int e = ebase + j;
                    sv[j] = (e < MAXT) ? sL[e] : 0.f;
                }
                suf[4] = sv[4];
                #pragma unroll
                for (int j = 3; j >= 0; j--) suf[j] = sv[j] + suf[j + 1];
                float ltot = suf[0];
                float accs = ltot;
                #pragma unroll
                for (int off = 1; off < 64; off <<= 1) {
                    float y = __shfl_down(accs, off, 64);
                    if (lane + off < 64) accs += y;
                }
                float after_lane = accs - ltot;
                int emin = 0x7fffffff;
                #pragma unroll
                for (int j = 0; j < 5; j++) {
                    int e = ebase + j;
                    if (e <= tp) {
                        float prod = after_lane + (suf[j] - sv[j]);
                        float sp = (e == tp) ? dval
                                             : fmaxf(0.f, sv[j] - fmaxf(0.f, uval - prod));
                        float inner = fmaxf(0.f, 1.f - prod - sp);
                        sL[e] = sp;
                        aL[e] = fminf(sp, inner);
                        // A[e] nonzero only where prod < 1 (prod monotone
                        // non-increasing => nonzeros form a suffix [e0..tp]).
                        if (prod < 1.f && e < emin) emin = e;
                    }
                }
                #pragma unroll
                for (int off = 32; off; off >>= 1) {
                    int o = __shfl_xor(emin, off, 64);
                    emin = o < emin ? o : emin;
                }
                if (lane == 0) e0S = emin;
            }
            __syncthreads();
            {
                const int e0 = e0S;
                float racc = 0.f;
                if (e0 <= tp) {
                    int i2s = e0 + ((wv - e0) & 3);
                    for (int i2 = i2s; i2 <= tp; i2 += 4)
                        racc += aL[i2] * bfbits2f(Vrow[i2 * SDIM + lane]);
                }
                red[wv][lane] = racc;
            }
            __syncthreads();
            if (wv == 0) {
                float rtv = red[0][lane] + red[1][lane] + red[2][lane] + red[3][lane];
                float rtn = __shfl_down(rtv, 1, 64);
                if ((lane & 1) == 0) {
                    unsigned short hb0 = f2bfbits(rtv);
                    unsigned short lb0 = f2bfbits(rtv - bfbits2f(hb0));
                    unsigned short hb1 = f2bfbits(rtn);
                    unsigned short lb1 = f2bfbits(rtn - bfbits2f(hb1));
                    unsigned u0 = (unsigned)hb0 | ((unsigned)lb0 << 16);
                    unsigned u1 = (unsigned)hb1 | ((unsigned)lb1 << 16);
                    int d0 = lane;
                    int ksi = d0 >> 5, q = (d0 & 31) >> 3, e = d0 & 7;
                    size_t fi = (((size_t)ms * 18 + ksi) * 64 + q * 16 + ns) * 8 + e;
                    astore64(AfCur64 + fi / 2,
                             (unsigned long long)u0 | ((unsigned long long)u1 << 32));
                }
                // release: drain this wave's rt stores, then publish epoch flag
                asm volatile("s_waitcnt vmcnt(0)" ::: "memory");
                if (lane == 0)
                    __hip_atomic_store(&rtcf[(ms * 16 + ns) * 16], (unsigned)t,
                                       __ATOMIC_RELAXED, __HIP_MEMORY_SCOPE_AGENT);
            } else if (wv == 1 && t - 1 >= 129) {
                const int tp = t - 1;
                float a = outs[64 + lane];
                float bvv = outs[128 + lane];
                float m = fmaxf(a, bvv);
                #pragma unroll
                for (int off = 32; off; off >>= 1) m = fmaxf(m, __shfl_xor(m, off, 64));
                float e = expf(a - m) + expf(bvv - m);
                #pragma unroll
                for (int off = 32; off; off >>= 1) e += __shfl_xor(e, off, 64);
                float ls = logf(e) + m;
                size_t base = ((size_t)(tp - 129) * BATCH + brow) * IDIM;
                if (isf32) {
                    ((float*)dout)[base + lane] = a - ls;
                    ((float*)dout)[base + lane + 64] = bvv - ls;
                } else {
                    ((bf16*)dout)[base + lane] = __float2bfloat16(a - ls);
                    ((bf16*)dout)[base + lane + 64] = __float2bfloat16(bvv - ls);
                }
            }
        }

        if (t == MAXT) break;   // iteration 259 exists only to run P2 for step 258

        const int use_x = (t < 129);
        __syncthreads();        // h A-frags staged (covers P0a; P2 already synced)

        // ---- P1a: gates MFMA, x + h K-slices ----
        floatx4 acc = {0.f, 0.f, 0.f, 0.f};
        const short8* wb  = WH + (size_t)nt * 22 * 64;
        const short8* wbl = WL + (size_t)nt * 22 * 64;
        if (use_x) {
            int m = lane & 15, q = lane >> 4;
            size_t xrow = ((size_t)t * BATCH + ms * 16 + m) * IDIM + q * 8;
            #pragma unroll
            for (int ks = 0; ks < 4; ks++) {
                short8 a;
                if (isf32) {
                    const float* xf = (const float*)x + xrow + ks * 32;
                    #pragma unroll
                    for (int i = 0; i < 8; i++) a[i] = (short)f2bfbits(xf[i]);
                } else {
                    a = *(const short8*)((const unsigned short*)x + xrow + ks * 32);
                }
                acc = __builtin_amdgcn_mfma_f32_16x16x32_bf16(a, wb[ks * 64 + lane], acc, 0, 0, 0);
                if (isf32)
                    acc = __builtin_amdgcn_mfma_f32_16x16x32_bf16(a, wbl[ks * 64 + lane], acc, 0, 0, 0);
            }
        }
        #pragma unroll 4
        for (int ksi = 2; ksi < 18; ksi++) {
            int ks = 4 + ksi;
            short8 ah  = *(const short8*)&Ahs[(ksi * 64 + lane) * 8];
            short8 al8 = *(const short8*)&Als[(ksi * 64 + lane) * 8];
            short8 bh = wb[ks * 64 + lane];
            acc = __builtin_amdgcn_mfma_f32_16x16x32_bf16(ah, bh, acc, 0, 0, 0);
            acc = __builtin_amdgcn_mfma_f32_16x16x32_bf16(al8, bh, acc, 0, 0, 0);
            if (isf32)
                acc = __builtin_amdgcn_mfma_f32_16x16x32_bf16(ah, wbl[ks * 64 + lane], acc, 0, 0, 0);
        }

        // ---- wait for rt(t-1) from the 16 row-flags of this group ----
        wait_rtf(rtcf, ms, (unsigned)t);

        // ---- P0b: stage rt A-frags (ksi 0..1) from buf cur, finish gates ----
        if (tid < 128) {
            int ksi = tid >> 6, l = tid & 63;
            const unsigned long long* ap =
                AfPc64 + ((size_t)(ms * 18 + ksi) * 64 + l) * 4;
            short8 ah, al8;
            unpack_frag(ap, ah, al8);
            *(short8*)&Ahs[(ksi * 64 + l) * 8] = ah;
            *(short8*)&Als[(ksi * 64 + l) * 8] = al8;
        }
        __syncthreads();
        #pragma unroll
        for (int ksi = 0; ksi < 2; ksi++) {
            int ks = 4 + ksi;
            short8 ah  = *(const short8*)&Ahs[(ksi * 64 + lane) * 8];
            short8 al8 = *(const short8*)&Als[(ksi * 64 + lane) * 8];
            short8 bh = wb[ks * 64 + lane];
            acc = __builtin_amdgcn_mfma_f32_16x16x32_bf16(ah, bh, acc, 0, 0, 0);
            acc = __builtin_amdgcn_mfma_f32_16x16x32_bf16(al8, bh, acc, 0, 0, 0);
            if (isf32)
                acc = __builtin_amdgcn_mfma_f32_16x16x32_bf16(ah, wbl[ks * 64 + lane], acc, 0, 0, 0);
        }

        {
            int n = lane & 15, m0 = (lane >> 4) * 4;
            #pragma unroll
            for (int r = 0; r < 4; r++) scr[wv][m0 + r][n] = acc[r];
        }
        __syncthreads();
        // cell epilogue: thread = (row r, local-u ul); c in one VGPR; h -> hl
        {
            int r = tid >> 4, ul = tid & 15;
            float4 g = *(const float4*)&scr[ul >> 2][r][(ul & 3) * 4];
            float4 bb = *(const float4*)&bcS[ul * 4];
            float c2 = sigmoidf_(g.y + bb.y) * cc + sigmoidf_(g.x + bb.x) * tanhf(g.z + bb.z);
            float h2 = sigmoidf_(g.w + bb.w) * tanhf(c2);
            cc = c2;
            hl[r][ul] = h2;
        }
        __syncthreads();   // hl ready; Ahs (MFMA staging) now dead -> pt overlay OK
        // publish h tile as packed uint64 frag stores (128 threads)
        if (tid < 128) {
            int r = tid >> 3, ulp = (tid & 7) * 2;
            float h0 = hl[r][ulp], h1 = hl[r][ulp + 1];
            unsigned short hb0 = f2bfbits(h0);
            unsigned short lb0 = f2bfbits(h0 - bfbits2f(hb0));
            unsigned short hb1 = f2bfbits(h1);
            unsigned short lb1 = f2bfbits(h1 - bfbits2f(hb1));
            unsigned u0 = (unsigned)hb0 | ((unsigned)lb0 << 16);
            unsigned u1 = (unsigned)hb1 | ((unsigned)lb1 << 16);
            int u_g = ns * 16 + ulp;
            int ksi2 = 2 + (u_g >> 5), q = (u_g & 31) >> 3, e = u_g & 7;
            size_t fi = (((size_t)ms * 18 + ksi2) * 64 + q * 16 + r) * 8 + e;
            astore64(AfPn64 + fi / 2, (unsigned long long)u0 | ((unsigned long long)u1 << 32));
        }
        // readout partials -> LDS tile pt[16][212]: Wr rows via ds_read_b128,
        // h cached in registers.
        {
            int jset = tid >> 4, r2 = tid & 15;
            float hreg[16];
            #pragma unroll
            for (int k = 0; k < 16; k++) hreg[k] = hl[r2][k];
            float* prow = pt + r2 * 212;
            #pragma unroll 4
            for (int i = 0; i < 13; i++) {
                int j = jset * 13 + i;
                short8 w0 = *(const short8*)&wrsl[j * 16];
                short8 w1 = *(const short8*)&wrsl[j * 16 + 8];
                float p = 0.f;
                #pragma unroll
                for (int k = 0; k < 8; k++) p += bfbits2f((unsigned short)w0[k]) * hreg[k];
                #pragma unroll
                for (int k = 0; k < 8; k++) p += bfbits2f((unsigned short)w1[k]) * hreg[8 + k];
                if (isf32) {
                    short8 l0 = *(const short8*)&wrslL[j * 16];
                    short8 l1 = *(const short8*)&wrslL[j * 16 + 8];
                    #pragma unroll
                    for (int k = 0; k < 8; k++) p += bfbits2f((unsigned short)l0[k]) * hreg[k];
                    #pragma unroll
                    for (int k = 0; k < 8; k++) p += bfbits2f((unsigned short)l1[k]) * hreg[8 + k];
                }
                prow[j] = p;
            }
        }
        __syncthreads();
        // coalesced publish: wave wv owns rows 4wv..4wv+3. For t<129 the ot
        // logits (j 64..191) are never consumed -> publish only j 0..63 and
        // 192..211. Safe WAR: the rt-flag wait above guaranteed the group's 16
        // P2 blocks consumed partials(t-1) (their pv loads complete before the
        // vmcnt drain preceding their flag store).
        {
            #pragma unroll
            for (int it = 0; it < 4; it++) {
                int rloc = wv * 4 + it;
                int row = ms * 16 + rloc;
                const float* pr = pt + rloc * 212;
                unsigned long long* pb64 =
                    (unsigned long long*)(part + (((size_t)row * 32) + ns) * PJ);
                if (use_x) {
                    if (lane < 32)
                        astore64(pb64 + lane, packf2(pr[2 * lane], pr[2 * lane + 1]));
                    else if (lane < 42) {
                        int l2 = lane - 32;   // u64 slots 96..105 = j 192..211
                        astore64(pb64 + 96 + l2,
                                 packf2(pr[192 + 2 * l2], pr[193 + 2 * l2]));
                    }
                } else {
                    astore64(pb64 + lane, packf2(pr[2 * lane], pr[2 * lane + 1]));
                    if (lane < 40)
                        astore64(pb64 + 64 + lane,
                                 packf2(pr[128 + 2 * lane], pr[129 + 2 * lane]));
                }
            }
        }
        group_barrier(flags, gbase, (unsigned)(t + 1));
    }
}

extern "C" void kernel_launch(void* const* d_in, const int* in_sizes, int n_in,
                              void* d_out, int out_size, void* d_ws, size_t ws_size,
                              hipStream_t stream) {
    const void* x   = d_in[0];
    const void* Wih = d_in[1];
    const void* bih = d_in[2];
    const void* Whh = d_in[3];
    const void* bhh = d_in[4];
    const void* Wr  = d_in[5];
    const void* br  = d_in[6];

    char* base = (char*)d_ws;
    size_t off = 0;
    int* flag = (int*)base;                                   off += 64;
    unsigned* flags = (unsigned*)(base + off);                off += 256 * 64 + 64;
    unsigned* rtcf = (unsigned*)(base + off);                 off += 128 * 64 + 64;
    unsigned short* WfH  = (unsigned short*)(base + off);     off += (size_t)G4 * KTOT * 2;
    unsigned short* WfL  = (unsigned short*)(base + off);     off += (size_t)G4 * KTOT * 2;
    unsigned short* WrBh = (unsigned short*)(base + off);     off += (size_t)208 * HDIM * 2;
    unsigned short* WrBl = (unsigned short*)(base + off);     off += (size_t)208 * HDIM * 2;
    float* bc   = (float*)(base + off);                       off += G4 * 4;
    float* brf  = (float*)(base + off);                       off += 1024;
    unsigned* AfP = (unsigned*)(base + off);                  size_t af_off = off;
                                                              off += (size_t)2 * AFRAG_U * 4;
    float* part = (float*)(base + off);                       off += (size_t)BATCH * 32 * PJ * 4;
    unsigned short* Vg = (unsigned short*)(base + off);       off += (size_t)BATCH * MAXT * SDIM * 2;
    // total ~15 MB

    hipMemsetAsync(base + 64, 0, 256 * 64 + 64 + 128 * 64 + 64, stream);  // flags + rtcf
    hipMemsetAsync(base + af_off, 0, (size_t)2 * AFRAG_U * 4, stream);    // A-frag buffers
    hipMemsetAsync(part, 0, (size_t)BATCH * 32 * PJ * 4, stream);         // stale-read hygiene

    detect_kernel<<<1, 64, 0, stream>>>((const unsigned short*)Wih, flag);
    prep_kernel<<<G4, 256, 0, stream>>>(Wih, bih, Whh, bhh, WfH, WfL, bc, flag);
    wr_prep_kernel<<<208, 256, 0, stream>>>(Wr, br, WrBh, WrBl, brf, flag);

    persist_kernel<<<NBLK, 256, 0, stream>>>(x, WfH, WfL, bc, WrBh, WrBl, brf,
                                             AfP, part, Vg, d_out, flag, flags, rtcf);

    (void)in_sizes; (void)n_in; (void)out_size; (void)ws_size;
}

// Round 4
// 3011.554 us; speedup vs baseline: 1.8321x; 1.3904x over previous
//
#include <hip/hip_runtime.h>
#include <hip/hip_bf16.h>
#include <math.h>

#define IDIM 128
#define HDIM 512
#define SDIM 64
#define BATCH 128
#define MAXT 259
#define G4 2048
#define KTOT 704    // 128 (x) + 64 (rt) + 512 (h)
#define ROUT 194    // 64 + 128 + 2
#define AFRAG_U 73728   // 8 mt * 18 ks * 64 lanes * 8 e (uints, hi|lo packed) per buffer
#define NBLK 256
#define NGATE 16    // gate blocks per group
#define PJ 224      // padded j-dim of part segment
#define PTJ 224     // pt row stride (14 j-tiles x 16)

typedef __hip_bfloat16 bf16;
typedef __attribute__((ext_vector_type(8))) short short8;
typedef __attribute__((ext_vector_type(4))) float floatx4;

__device__ __forceinline__ float sigmoidf_(float v) { return 1.f / (1.f + expf(-v)); }
__device__ __forceinline__ float b2f(bf16 v) { return __bfloat162float(v); }
__device__ __forceinline__ float load_in(const void* p, size_t i, int isf32) {
    return isf32 ? ((const float*)p)[i] : b2f(((const bf16*)p)[i]);
}
__device__ __forceinline__ unsigned short f2bfbits(float v) {
    unsigned u = __builtin_bit_cast(unsigned, v);
    unsigned r = (u + 0x7FFFu + ((u >> 16) & 1u)) >> 16;
    return (unsigned short)r;
}
__device__ __forceinline__ float bfbits2f(unsigned short b) {
    return __builtin_bit_cast(float, (unsigned)b << 16);
}
__device__ __forceinline__ unsigned aload(const unsigned* p) {
    return __hip_atomic_load(p, __ATOMIC_RELAXED, __HIP_MEMORY_SCOPE_AGENT);
}
__device__ __forceinline__ unsigned long long aload64(const unsigned long long* p) {
    return __hip_atomic_load(p, __ATOMIC_RELAXED, __HIP_MEMORY_SCOPE_AGENT);
}
__device__ __forceinline__ void astore64(unsigned long long* p, unsigned long long v) {
    __hip_atomic_store(p, v, __ATOMIC_RELAXED, __HIP_MEMORY_SCOPE_AGENT);
}
__device__ __forceinline__ unsigned long long packf2(float a, float b) {
    return (unsigned long long)__builtin_bit_cast(unsigned, a)
         | ((unsigned long long)__builtin_bit_cast(unsigned, b) << 32);
}
__device__ __forceinline__ void unpack_frag(const unsigned long long* ap,
                                            short8& ah, short8& al) {
    #pragma unroll
    for (int j = 0; j < 4; j++) {
        unsigned long long q = aload64(ap + j);
        unsigned u0 = (unsigned)q, u1 = (unsigned)(q >> 32);
        ah[2 * j]     = (short)(u0 & 0xffffu);
        al[2 * j]     = (short)(u0 >> 16);
        ah[2 * j + 1] = (short)(u1 & 0xffffu);
        al[2 * j + 1] = (short)(u1 >> 16);
    }
}

// Poll 16 consecutive epoch flags (stride-16 uints) until all >= tgt.
// Producers store flags AFTER a per-wave vmcnt drain of their data stores
// (+ __syncthreads across the block) -> flag >= tgt implies data visible.
__device__ __forceinline__ void wait_flags16(const unsigned* f, int base16,
                                             unsigned tgt) {
    if (threadIdx.x < 16) {
        while (aload(&f[(base16 + (int)threadIdx.x) * 16]) < tgt)
            __builtin_amdgcn_s_sleep(1);
    }
    __atomic_signal_fence(__ATOMIC_SEQ_CST);
    __syncthreads();
}

// dtype detect (defensive): f32 data has random low halves -> bf16-exp >= 0x8F
__global__ void detect_kernel(const unsigned short* __restrict__ w, int* __restrict__ flag) {
    if (threadIdx.x == 0) {
        int isf32 = 0;
        for (int i = 0; i < 256; i++) {
            int e = (w[i] >> 7) & 0xFF;
            if (e >= 0x8F) isf32 = 1;
        }
        *flag = isf32;
    }
}

// Gate-interleaved combined weights in B-fragment layout (hi/lo bf16 split).
__global__ void prep_kernel(const void* __restrict__ Wih, const void* __restrict__ bih,
                            const void* __restrict__ Whh, const void* __restrict__ bhh,
                            unsigned short* __restrict__ WfH, unsigned short* __restrict__ WfL,
                            float* __restrict__ bc, const int* __restrict__ flag) {
    int isf32 = *flag;
    int jp = blockIdx.x;
    int u = jp >> 2, gate = jp & 3;
    int src = gate * HDIM + u;
    int jt = jp >> 4, jn = jp & 15;
    for (int k = threadIdx.x; k < KTOT; k += blockDim.x) {
        float v = (k < 192) ? load_in(Wih, (size_t)src * 192 + k, isf32)
                            : load_in(Whh, (size_t)src * HDIM + (k - 192), isf32);
        unsigned short hi = f2bfbits(v);
        unsigned short lo = f2bfbits(v - bfbits2f(hi));
        int ks = k >> 5, q = (k & 31) >> 3, e = k & 7;
        size_t d = (((size_t)jt * 22 + ks) * 64 + (q * 16 + jn)) * 8 + e;
        WfH[d] = hi;
        WfL[d] = lo;
    }
    if (threadIdx.x == 0)
        bc[jp] = load_in(bih, src, isf32) + load_in(bhh, src, isf32);
}

// Wr -> row-major bf16 hi/lo (224 rows, rows >= 194 zero) + brf f32 (padded).
__global__ void wr_prep_kernel(const void* __restrict__ Wr, const void* __restrict__ br,
                               unsigned short* __restrict__ WrBh, unsigned short* __restrict__ WrBl,
                               float* __restrict__ brf, const int* __restrict__ flag) {
    int isf32 = *flag;
    int j = blockIdx.x;
    for (int k = threadIdx.x; k < HDIM; k += blockDim.x) {
        float v = (j < ROUT) ? load_in(Wr, (size_t)j * HDIM + k, isf32) : 0.f;
        unsigned short hi = f2bfbits(v);
        WrBh[(size_t)j * HDIM + k] = hi;
        WrBl[(size_t)j * HDIM + k] = f2bfbits(v - bfbits2f(hi));
    }
    if (threadIdx.x == 0) brf[j] = (j < ROUT) ? load_in(br, j, isf32) : 0.f;
}

// ------ persistent kernel (R15: dedicated P2 blocks, split flags) ------
// 256 blocks x 256 threads, 8 groups of 32. Group g = blk>>5 owns batch rows
// 16g..16g+15. Blocks ns<16 = GATE blocks (gb=ns, j-cols 128gb..+128, h-cols
// 32gb..+32). Blocks ns>=16 = dedicated P2 blocks (pb=ns-16, row 16g+pb),
// free-running on flags. Per gate iter: wait hfl>=t (h(t-1) ready) -> stage +
// x/h MFMA -> wait rtf>=t (rt(t-1) from P2) -> finish -> epilogue -> h publish
// + drain + hfl=t+1 -> MFMA readout -> part publish + drain + pfl=t+1.
// P2 step t: wait pfl>=t+1 -> reduce 16 partials -> stack scan (sparse suffix)
// -> einsum -> rt(t) -> AfP buf (t+1)&1 + rtf=t+1; dout row for t>=129.
__global__ __launch_bounds__(256) void persist_kernel(
        const void* __restrict__ x,
        const unsigned short* __restrict__ WfH, const unsigned short* __restrict__ WfL,
        const float* __restrict__ bc,
        const unsigned short* __restrict__ WrBh, const unsigned short* __restrict__ WrBl,
        const float* __restrict__ brf,
        unsigned* __restrict__ AfP,          // 2 x AFRAG_U uints (hi | lo<<16)
        float* __restrict__ part,            // [128 rows][16 gb][PJ] f32
        unsigned short* __restrict__ Vg,     // [128][259][64] bf16, row-private
        void* __restrict__ dout, const int* __restrict__ flag,
        unsigned* __restrict__ hfl, unsigned* __restrict__ pfl,
        unsigned* __restrict__ rtf) {
    __shared__ __align__(16) short Ahs[18 * 64 * 8];          // staged A hi; pt overlay
    __shared__ __align__(16) short Als[18 * 64 * 8];          // staged A lo
    __shared__ __align__(16) unsigned short wrslB[14 * 64 * 8];   // Wr hi, B-frag layout
    __shared__ __align__(16) unsigned short wrslBL[14 * 64 * 8];  // Wr lo, B-frag layout
    __shared__ __align__(16) float scr[8][16][20];
    __shared__ __align__(16) unsigned short hlh[16 * 40];     // h hi bf16 (pad 40)
    __shared__ __align__(16) unsigned short hll[16 * 40];     // h lo bf16
    __shared__ __align__(16) float outs[208];
    __shared__ __align__(16) float sL[324];
    __shared__ __align__(16) float aL[324];
    __shared__ __align__(16) float red[4][64];
    __shared__ __align__(16) float brS[208];
    __shared__ __align__(16) float bcS[128];
    __shared__ int e0S;

    const int tid = threadIdx.x, lane = tid & 63, wv = tid >> 6;
    const int blk = blockIdx.x, ms = blk >> 5, ns = blk & 31;
    const int isf32 = *flag;
    float* const pt = (float*)Ahs;       // 16 x 224 f32 overlay (14.3KB <= 18.4KB)

    const int is_gate = (ns < 16);
    const int gb = ns;                   // gate block index (when is_gate)
    const int pb = ns - 16;              // P2 index (when !is_gate)
    const int p2row = ms * 16 + pb;      // P2's batch row

    if (is_gate) {
        // Wr slice in B-frag layout: tile jt (14), lane l, elem e ->
        // row j = jt*16 + (l&15), col k = gb*32 + (l>>4)*8 + e.
        for (int i = tid; i < 14 * 64 * 8; i += 256) {
            int jt = i >> 9, l = (i >> 3) & 63, e = i & 7;
            size_t src = (size_t)(jt * 16 + (l & 15)) * HDIM + gb * 32 + (l >> 4) * 8 + e;
            wrslB[i]  = WrBh[src];
            wrslBL[i] = WrBl[src];
        }
        if (tid < 128) bcS[tid] = bc[gb * 128 + tid];
    } else {
        for (int i = tid; i < 208; i += 256) brS[i] = brf[i];
        for (int i = tid; i < 324; i += 256) { sL[i] = 0.f; aL[i] = 0.f; }
    }
    __syncthreads();

    if (is_gate) {
        // =========================== GATE BLOCK ===========================
        const short8* WH = (const short8*)WfH;
        const short8* WL = (const short8*)WfL;
        const int jt0 = gb * 8 + wv, jt1 = gb * 8 + 4 + wv;
        const short8* wb0  = WH + (size_t)jt0 * 22 * 64;
        const short8* wb1  = WH + (size_t)jt1 * 22 * 64;
        const short8* wbl0 = WL + (size_t)jt0 * 22 * 64;
        const short8* wbl1 = WL + (size_t)jt1 * 22 * 64;
        float cc0 = 0.f, cc1 = 0.f;

        for (int t = 0; t < MAXT; t++) {
            const int cur = t & 1, nxt = cur ^ 1;
            const unsigned long long* AfPc64 =
                (const unsigned long long*)(AfP + (size_t)cur * AFRAG_U);
            unsigned long long* AfPn64 =
                (unsigned long long*)(AfP + (size_t)nxt * AFRAG_U);
            const int use_x = (t < 129);

            // wait h(t-1) frags from all 16 gate blocks of this group
            wait_flags16(hfl, ms * 16, (unsigned)t);

            // P0a: stage h A-frags (ksi 2..17) from buf cur
            #pragma unroll
            for (int i0 = 0; i0 < 4; i0++) {
                int i = i0 * 256 + tid;
                int ksi = 2 + (i >> 6), l = i & 63;
                const unsigned long long* ap =
                    AfPc64 + ((size_t)(ms * 18 + ksi) * 64 + l) * 4;
                short8 ah, al8;
                unpack_frag(ap, ah, al8);
                *(short8*)&Ahs[(ksi * 64 + l) * 8] = ah;
                *(short8*)&Als[(ksi * 64 + l) * 8] = al8;
            }
            __syncthreads();

            // P1: gates MFMA, x + h K-slices, two j-tiles per wave
            floatx4 acc0 = {0.f, 0.f, 0.f, 0.f};
            floatx4 acc1 = {0.f, 0.f, 0.f, 0.f};
            if (use_x) {
                int m = lane & 15, q = lane >> 4;
                size_t xrow = ((size_t)t * BATCH + ms * 16 + m) * IDIM + q * 8;
                #pragma unroll
                for (int ks = 0; ks < 4; ks++) {
                    short8 a;
                    if (isf32) {
                        const float* xf = (const float*)x + xrow + ks * 32;
                        #pragma unroll
                        for (int i = 0; i < 8; i++) a[i] = (short)f2bfbits(xf[i]);
                    } else {
                        a = *(const short8*)((const unsigned short*)x + xrow + ks * 32);
                    }
                    acc0 = __builtin_amdgcn_mfma_f32_16x16x32_bf16(a, wb0[ks * 64 + lane], acc0, 0, 0, 0);
                    acc1 = __builtin_amdgcn_mfma_f32_16x16x32_bf16(a, wb1[ks * 64 + lane], acc1, 0, 0, 0);
                    if (isf32) {
                        acc0 = __builtin_amdgcn_mfma_f32_16x16x32_bf16(a, wbl0[ks * 64 + lane], acc0, 0, 0, 0);
                        acc1 = __builtin_amdgcn_mfma_f32_16x16x32_bf16(a, wbl1[ks * 64 + lane], acc1, 0, 0, 0);
                    }
                }
            }
            #pragma unroll 4
            for (int ksi = 2; ksi < 18; ksi++) {
                int ks = 4 + ksi;
                short8 ah  = *(const short8*)&Ahs[(ksi * 64 + lane) * 8];
                short8 al8 = *(const short8*)&Als[(ksi * 64 + lane) * 8];
                short8 bh0 = wb0[ks * 64 + lane];
                short8 bh1 = wb1[ks * 64 + lane];
                acc0 = __builtin_amdgcn_mfma_f32_16x16x32_bf16(ah, bh0, acc0, 0, 0, 0);
                acc0 = __builtin_amdgcn_mfma_f32_16x16x32_bf16(al8, bh0, acc0, 0, 0, 0);
                acc1 = __builtin_amdgcn_mfma_f32_16x16x32_bf16(ah, bh1, acc1, 0, 0, 0);
                acc1 = __builtin_amdgcn_mfma_f32_16x16x32_bf16(al8, bh1, acc1, 0, 0, 0);
                if (isf32) {
                    acc0 = __builtin_amdgcn_mfma_f32_16x16x32_bf16(ah, wbl0[ks * 64 + lane], acc0, 0, 0, 0);
                    acc1 = __builtin_amdgcn_mfma_f32_16x16x32_bf16(ah, wbl1[ks * 64 + lane], acc1, 0, 0, 0);
                }
            }

            // wait rt(t-1) from this group's 16 P2 rows
            wait_flags16(rtf, ms * 16, (unsigned)t);

            // P0b: stage rt A-frags (ksi 0..1), finish gates
            if (tid < 128) {
                int ksi = tid >> 6, l = tid & 63;
                const unsigned long long* ap =
                    AfPc64 + ((size_t)(ms * 18 + ksi) * 64 + l) * 4;
                short8 ah, al8;
                unpack_frag(ap, ah, al8);
                *(short8*)&Ahs[(ksi * 64 + l) * 8] = ah;
                *(short8*)&Als[(ksi * 64 + l) * 8] = al8;
            }
            __syncthreads();
            #pragma unroll
            for (int ksi = 0; ksi < 2; ksi++) {
                int ks = 4 + ksi;
                short8 ah  = *(const short8*)&Ahs[(ksi * 64 + lane) * 8];
                short8 al8 = *(const short8*)&Als[(ksi * 64 + lane) * 8];
                short8 bh0 = wb0[ks * 64 + lane];
                short8 bh1 = wb1[ks * 64 + lane];
                acc0 = __builtin_amdgcn_mfma_f32_16x16x32_bf16(ah, bh0, acc0, 0, 0, 0);
                acc0 = __builtin_amdgcn_mfma_f32_16x16x32_bf16(al8, bh0, acc0, 0, 0, 0);
                acc1 = __builtin_amdgcn_mfma_f32_16x16x32_bf16(ah, bh1, acc1, 0, 0, 0);
                acc1 = __builtin_amdgcn_mfma_f32_16x16x32_bf16(al8, bh1, acc1, 0, 0, 0);
                if (isf32) {
                    acc0 = __builtin_amdgcn_mfma_f32_16x16x32_bf16(ah, wbl0[ks * 64 + lane], acc0, 0, 0, 0);
                    acc1 = __builtin_amdgcn_mfma_f32_16x16x32_bf16(ah, wbl1[ks * 64 + lane], acc1, 0, 0, 0);
                }
            }
            {
                int n = lane & 15, m0 = (lane >> 4) * 4;
                #pragma unroll
                for (int r = 0; r < 4; r++) scr[wv][m0 + r][n] = acc0[r];
                #pragma unroll
                for (int r = 0; r < 4; r++) scr[wv + 4][m0 + r][n] = acc1[r];
            }
            __syncthreads();
            // cell epilogue: thread = (row r, units p and p+16); h -> hlh/hll bf16
            {
                int r = tid >> 4, p = tid & 15;
                float4 g = *(const float4*)&scr[p >> 2][r][(p & 3) * 4];
                float4 bb = *(const float4*)&bcS[p * 4];
                float c2 = sigmoidf_(g.y + bb.y) * cc0 + sigmoidf_(g.x + bb.x) * tanhf(g.z + bb.z);
                float h2 = sigmoidf_(g.w + bb.w) * tanhf(c2);
                cc0 = c2;
                unsigned short hi0 = f2bfbits(h2);
                hlh[r * 40 + p] = hi0;
                hll[r * 40 + p] = f2bfbits(h2 - bfbits2f(hi0));
                int u1 = p + 16;
                float4 g1 = *(const float4*)&scr[u1 >> 2][r][(u1 & 3) * 4];
                float4 bb1 = *(const float4*)&bcS[u1 * 4];
                float c21 = sigmoidf_(g1.y + bb1.y) * cc1 + sigmoidf_(g1.x + bb1.x) * tanhf(g1.z + bb1.z);
                float h21 = sigmoidf_(g1.w + bb1.w) * tanhf(c21);
                cc1 = c21;
                unsigned short hi1 = f2bfbits(h21);
                hlh[r * 40 + u1] = hi1;
                hll[r * 40 + u1] = f2bfbits(h21 - bfbits2f(hi1));
            }
            __syncthreads();
            // h publish: 256 threads, 2 cols each (already-converted bf16 hi/lo)
            {
                int rr = tid >> 4, pp = tid & 15;
                unsigned short hb0 = hlh[rr * 40 + 2 * pp];
                unsigned short lb0 = hll[rr * 40 + 2 * pp];
                unsigned short hb1 = hlh[rr * 40 + 2 * pp + 1];
                unsigned short lb1 = hll[rr * 40 + 2 * pp + 1];
                unsigned u0 = (unsigned)hb0 | ((unsigned)lb0 << 16);
                unsigned u1 = (unsigned)hb1 | ((unsigned)lb1 << 16);
                int u_g = gb * 32 + 2 * pp;
                int ksi2 = 2 + (u_g >> 5), q = (u_g & 31) >> 3, e = u_g & 7;
                size_t fi = (((size_t)ms * 18 + ksi2) * 64 + q * 16 + rr) * 8 + e;
                astore64(AfPn64 + fi / 2, (unsigned long long)u0 | ((unsigned long long)u1 << 32));
            }
            // drain h stores, publish hfl (unblocks the group's next iteration)
            asm volatile("s_waitcnt vmcnt(0)" ::: "memory");
            __syncthreads();
            if (tid == 0)
                __hip_atomic_store(&hfl[(ms * 16 + gb) * 16], (unsigned)(t + 1),
                                   __ATOMIC_RELAXED, __HIP_MEMORY_SCOPE_AGENT);

            // readout partials via MFMA: pt[16][224] = h(bf16 hi/lo) @ WrB
            {
                int m = lane & 15, q = lane >> 4;
                short8 ahh = *(const short8*)&hlh[m * 40 + q * 8];
                short8 ahl = *(const short8*)&hll[m * 40 + q * 8];
                int n = lane & 15, m0 = (lane >> 4) * 4;
                for (int jt = wv; jt < 14; jt += 4) {
                    const short8* bB  = (const short8*)&wrslB[((size_t)jt * 64 + lane) * 8];
                    const short8* bBl = (const short8*)&wrslBL[((size_t)jt * 64 + lane) * 8];
                    floatx4 accR = {0.f, 0.f, 0.f, 0.f};
                    short8 bh = *bB;
                    accR = __builtin_amdgcn_mfma_f32_16x16x32_bf16(ahh, bh, accR, 0, 0, 0);
                    accR = __builtin_amdgcn_mfma_f32_16x16x32_bf16(ahl, bh, accR, 0, 0, 0);
                    if (isf32) {
                        short8 bl = *bBl;
                        accR = __builtin_amdgcn_mfma_f32_16x16x32_bf16(ahh, bl, accR, 0, 0, 0);
                        accR = __builtin_amdgcn_mfma_f32_16x16x32_bf16(ahl, bl, accR, 0, 0, 0);
                    }
                    #pragma unroll
                    for (int ri = 0; ri < 4; ri++)
                        pt[(m0 + ri) * PTJ + jt * 16 + n] = accR[ri];
                }
            }
            __syncthreads();
            // part publish: wave wv rows 4wv..4wv+3; t<129 trim (ot unused)
            {
                #pragma unroll
                for (int it = 0; it < 4; it++) {
                    int rloc = wv * 4 + it;
                    int prow_ = ms * 16 + rloc;
                    const float* pr = pt + rloc * PTJ;
                    unsigned long long* pb64 =
                        (unsigned long long*)(part + (((size_t)prow_ * NGATE) + gb) * PJ);
                    if (use_x) {
                        if (lane < 32)
                            astore64(pb64 + lane, packf2(pr[2 * lane], pr[2 * lane + 1]));
                        else if (lane < 42) {
                            int l2 = lane - 32;   // u64 slots 96..105 = j 192..211
                            astore64(pb64 + 96 + l2,
                                     packf2(pr[192 + 2 * l2], pr[193 + 2 * l2]));
                        }
                    } else {
                        astore64(pb64 + lane, packf2(pr[2 * lane], pr[2 * lane + 1]));
                        if (lane < 40)
                            astore64(pb64 + 64 + lane,
                                     packf2(pr[128 + 2 * lane], pr[129 + 2 * lane]));
                    }
                }
            }
            // drain part stores, publish pfl (consumed only by P2 blocks)
            asm volatile("s_waitcnt vmcnt(0)" ::: "memory");
            __syncthreads();
            if (tid == 0)
                __hip_atomic_store(&pfl[(ms * 16 + gb) * 16], (unsigned)(t + 1),
                                   __ATOMIC_RELAXED, __HIP_MEMORY_SCOPE_AGENT);
        }
    } else {
        // ============================ P2 BLOCK ============================
        unsigned short* Vrow = Vg + (size_t)p2row * MAXT * SDIM;
        for (int t = 0; t < MAXT; t++) {
            unsigned long long* AfPn64 =
                (unsigned long long*)(AfP + (size_t)((t + 1) & 1) * AFRAG_U);

            // wait part(t) from all 16 gate blocks of this group
            wait_flags16(pfl, ms * 16, (unsigned)(t + 1));

            if (tid < 208) {
                const unsigned* pb2 = (const unsigned*)part
                                    + (size_t)p2row * NGATE * PJ + tid;
                float s4 = brS[tid];
                #pragma unroll
                for (int g = 0; g < NGATE; g++)
                    s4 += __builtin_bit_cast(float, aload(pb2 + (size_t)g * PJ));
                outs[tid] = s4;
            }
            __syncthreads();
            if (wv == 0) {
                float uval = sigmoidf_(outs[192]);
                float dval = sigmoidf_(outs[193]);
                Vrow[t * SDIM + lane] = f2bfbits(outs[lane]);
                int ebase = lane * 5;
                float sv[5], suf[5];
                #pragma unroll
                for (int j = 0; j < 5; j++) {
                    int e = ebase + j;
                    sv[j] = (e < MAXT) ? sL[e] : 0.f;
                }
                suf[4] = sv[4];
                #pragma unroll
                for (int j = 3; j >= 0; j--) suf[j] = sv[j] + suf[j + 1];
                float ltot = suf[0];
                float accs = ltot;
                #pragma unroll
                for (int off = 1; off < 64; off <<= 1) {
                    float y = __shfl_down(accs, off, 64);
                    if (lane + off < 64) accs += y;
                }
                float after_lane = accs - ltot;
                int emin = 0x7fffffff;
                #pragma unroll
                for (int j = 0; j < 5; j++) {
                    int e = ebase + j;
                    if (e <= t) {
                        float prod = after_lane + (suf[j] - sv[j]);
                        float sp = (e == t) ? dval
                                            : fmaxf(0.f, sv[j] - fmaxf(0.f, uval - prod));
                        float inner = fmaxf(0.f, 1.f - prod - sp);
                        sL[e] = sp;
                        aL[e] = fminf(sp, inner);
                        // A[e] nonzero only where prod < 1 (monotone suffix)
                        if (prod < 1.f && e < emin) emin = e;
                    }
                }
                #pragma unroll
                for (int off = 32; off; off >>= 1) {
                    int o = __shfl_xor(emin, off, 64);
                    emin = o < emin ? o : emin;
                }
                if (lane == 0) e0S = emin;
            }
            __syncthreads();
            {
                const int e0 = e0S;
                float racc = 0.f;
                if (e0 <= t) {
                    int i2s = e0 + ((wv - e0) & 3);
                    for (int i2 = i2s; i2 <= t; i2 += 4)
                        racc += aL[i2] * bfbits2f(Vrow[i2 * SDIM + lane]);
                }
                red[wv][lane] = racc;
            }
            __syncthreads();
            if (wv == 0) {
                float rtv = red[0][lane] + red[1][lane] + red[2][lane] + red[3][lane];
                float rtn = __shfl_down(rtv, 1, 64);
                if ((lane & 1) == 0) {
                    unsigned short hb0 = f2bfbits(rtv);
                    unsigned short lb0 = f2bfbits(rtv - bfbits2f(hb0));
                    unsigned short hb1 = f2bfbits(rtn);
                    unsigned short lb1 = f2bfbits(rtn - bfbits2f(hb1));
                    unsigned u0 = (unsigned)hb0 | ((unsigned)lb0 << 16);
                    unsigned u1 = (unsigned)hb1 | ((unsigned)lb1 << 16);
                    int d0 = lane;
                    int ksi = d0 >> 5, q = (d0 & 31) >> 3, e = d0 & 7;
                    size_t fi = (((size_t)ms * 18 + ksi) * 64 + q * 16 + pb) * 8 + e;
                    astore64(AfPn64 + fi / 2,
                             (unsigned long long)u0 | ((unsigned long long)u1 << 32));
                }
                asm volatile("s_waitcnt vmcnt(0)" ::: "memory");
                if (lane == 0)
                    __hip_atomic_store(&rtf[(ms * 16 + pb) * 16], (unsigned)(t + 1),
                                       __ATOMIC_RELAXED, __HIP_MEMORY_SCOPE_AGENT);
            } else if (wv == 1 && t >= 129) {
                float a = outs[64 + lane];
                float bvv = outs[128 + lane];
                float m = fmaxf(a, bvv);
                #pragma unroll
                for (int off = 32; off; off >>= 1) m = fmaxf(m, __shfl_xor(m, off, 64));
                float e = expf(a - m) + expf(bvv - m);
                #pragma unroll
                for (int off = 32; off; off >>= 1) e += __shfl_xor(e, off, 64);
                float ls = logf(e) + m;
                size_t base = ((size_t)(t - 129) * BATCH + p2row) * IDIM;
                if (isf32) {
                    ((float*)dout)[base + lane] = a - ls;
                    ((float*)dout)[base + lane + 64] = bvv - ls;
                } else {
                    ((bf16*)dout)[base + lane] = __float2bfloat16(a - ls);
                    ((bf16*)dout)[base + lane + 64] = __float2bfloat16(bvv - ls);
                }
            }
        }
    }
}

extern "C" void kernel_launch(void* const* d_in, const int* in_sizes, int n_in,
                              void* d_out, int out_size, void* d_ws, size_t ws_size,
                              hipStream_t stream) {
    const void* x   = d_in[0];
    const void* Wih = d_in[1];
    const void* bih = d_in[2];
    const void* Whh = d_in[3];
    const void* bhh = d_in[4];
    const void* Wr  = d_in[5];
    const void* br  = d_in[6];

    char* base = (char*)d_ws;
    size_t off = 0;
    int* flag = (int*)base;                                   off += 64;
    unsigned* hfl = (unsigned*)(base + off);                  off += 128 * 64 + 64;
    unsigned* pfl = (unsigned*)(base + off);                  off += 128 * 64 + 64;
    unsigned* rtf = (unsigned*)(base + off);                  off += 128 * 64 + 64;
    unsigned short* WfH  = (unsigned short*)(base + off);     off += (size_t)G4 * KTOT * 2;
    unsigned short* WfL  = (unsigned short*)(base + off);     off += (size_t)G4 * KTOT * 2;
    unsigned short* WrBh = (unsigned short*)(base + off);     off += (size_t)224 * HDIM * 2;
    unsigned short* WrBl = (unsigned short*)(base + off);     off += (size_t)224 * HDIM * 2;
    float* bc   = (float*)(base + off);                       off += G4 * 4;
    float* brf  = (float*)(base + off);                       off += 1024;
    unsigned* AfP = (unsigned*)(base + off);                  size_t af_off = off;
                                                              off += (size_t)2 * AFRAG_U * 4;
    float* part = (float*)(base + off);                       off += (size_t)BATCH * NGATE * PJ * 4;
    unsigned short* Vg = (unsigned short*)(base + off);       off += (size_t)BATCH * MAXT * SDIM * 2;
    // total ~14 MB

    hipMemsetAsync(base + 64, 0, 3 * (128 * 64 + 64), stream);         // hfl/pfl/rtf
    hipMemsetAsync(base + af_off, 0, (size_t)2 * AFRAG_U * 4, stream); // A-frag buffers
    hipMemsetAsync(part, 0, (size_t)BATCH * NGATE * PJ * 4, stream);   // stale-read hygiene

    detect_kernel<<<1, 64, 0, stream>>>((const unsigned short*)Wih, flag);
    prep_kernel<<<G4, 256, 0, stream>>>(Wih, bih, Whh, bhh, WfH, WfL, bc, flag);
    wr_prep_kernel<<<224, 256, 0, stream>>>(Wr, br, WrBh, WrBl, brf, flag);

    persist_kernel<<<NBLK, 256, 0, stream>>>(x, WfH, WfL, bc, WrBh, WrBl, brf,
                                             AfP, part, Vg, d_out, flag,
                                             hfl, pfl, rtf);

    (void)in_sizes; (void)n_in; (void)out_size; (void)ws_size;
}